// Round 2
// baseline (49200.589 us; speedup 1.0000x reference)
//
#include <hip/hip_runtime.h>
#include <math.h>

// Problem constants
#define BATCH 128
#define TT 800
#define SL 64          // sent_max_len L
#define AA 60          // alphabet
#define HH 400         // hidden
#define KK 10          // mixture components
#define MB 16          // batch per group
#define NG 8           // groups (NG*MB == BATCH)
#define NWG 16         // gate WGs per group (window merged in)
#define UPW 25         // hidden units per WG
#define NTHR 512
#define HP 17          // padded LDS batch stride for hbuf (bank-conflict-free both ways)

// d_out offsets (flat fp32, reference return order)
#define O_HF   (BATCH*TT*HH)
#define O_CF   (O_HF + BATCH*HH)
#define O_WIN  (O_CF + BATCH*HH)
#define O_WF   (O_WIN + BATCH*TT*AA)
#define O_KF   (O_WF + BATCH*AA)
#define O_PHI  (O_KF + BATCH*KK)

// ws layout (floats): [0..15]=cnt(int, one per group), 16: h_ws [NG][2][HH][MB]

__device__ __forceinline__ float gld(const float* p) {
  return __hip_atomic_load(p, __ATOMIC_RELAXED, __HIP_MEMORY_SCOPE_AGENT);
}
__device__ __forceinline__ void gst(float* p, float v) {
  __hip_atomic_store(p, v, __ATOMIC_RELAXED, __HIP_MEMORY_SCOPE_AGENT);
}
// spin with bail-out so a sync bug fails visibly instead of hanging
__device__ __forceinline__ int spin_ge(int* p, int target) {
  for (int it = 0; it < (1 << 23); ++it) {
    if (__hip_atomic_load(p, __ATOMIC_ACQUIRE, __HIP_MEMORY_SCOPE_AGENT) >= target)
      return 1;
  }
  return 0;
}

__global__ void init_ws(int* wsi) {
  if (threadIdx.x < 16) wsi[threadIdx.x] = 0;
}

__global__ __launch_bounds__(NTHR) void lstm_persist(
    const float* __restrict__ strks, const float* __restrict__ onehots,
    const float* __restrict__ sents_m, const float* __restrict__ w_prev,
    const float* __restrict__ k_prev, const float* __restrict__ h0,
    const float* __restrict__ c0,
    const float* __restrict__ W_ih, const float* __restrict__ b_ih,
    const float* __restrict__ W_hh, const float* __restrict__ b_hh,
    const float* __restrict__ Wp, const float* __restrict__ bp,
    float* __restrict__ out, float* ws)
{
  const int g   = blockIdx.x / NWG;
  const int wg  = blockIdx.x % NWG;
  const int tid = threadIdx.x;
  const int b0  = g * MB;
  int* cnt   = ((int*)ws) + g;
  float* hws = ws + 16 + (size_t)g * (2*HH*MB);

  __shared__ float hbuf[HH*HP];        // [r][b] padded
  __shared__ float wbuf[AA*MB];        // [a][b]
  __shared__ float pbuf[3*KK*MB];      // [j][b]
  __shared__ float av[KK*MB], bv[KK*MB], kbuf[KK*MB];
  __shared__ float phibuf[(SL+1)*MB];  // [u][b]
  __shared__ float scalebuf[MB];
  __shared__ int s_ok;

  // gate-thread identity: b-major so W_hh loads broadcast across 16 batch lanes
  const int b  = tid & 15;
  const int ul = tid >> 4;             // [0,32)
  const bool act = (ul < UPW);
  const int unit = wg*UPW + (act ? ul : 0);
  float creg = act ? c0[(size_t)(b0+b)*HH + unit] : 0.f;
  const float* wip0 = W_ih + (size_t)(unit)*63;
  const float* wip1 = W_ih + (size_t)(HH+unit)*63;
  const float* wip2 = W_ih + (size_t)(2*HH+unit)*63;
  const float* wip3 = W_ih + (size_t)(3*HH+unit)*63;
  const float* whp0 = W_hh + (size_t)(unit)*HH;
  const float* whp1 = W_hh + (size_t)(HH+unit)*HH;
  const float* whp2 = W_hh + (size_t)(2*HH+unit)*HH;
  const float* whp3 = W_hh + (size_t)(3*HH+unit)*HH;
  const float bias0 = b_ih[unit]      + b_hh[unit];
  const float bias1 = b_ih[HH+unit]   + b_hh[HH+unit];
  const float bias2 = b_ih[2*HH+unit] + b_hh[2*HH+unit];
  const float bias3 = b_ih[3*HH+unit] + b_hh[3*HH+unit];

  // init window state (identical in every WG -> deterministic redundant compute)
  for (int i = tid; i < KK*MB; i += NTHR)
    kbuf[i] = k_prev[(size_t)(b0+(i&15))*KK + (i>>4)];
  if (tid < MB) {
    float s = 0.f;
    for (int l = 0; l < SL; ++l) s += sents_m[(size_t)(b0+tid)*SL + l];
    scalebuf[tid] = (float)SL / s;
  }

  // iteration t: stage h_{t-1}; window(t-1) [uses h_{t-1} -> w_{t-1}]; gates(t)
  for (int t = 0; t <= TT; ++t) {
    if (t == 0) {
      for (int i = tid; i < HH*MB; i += NTHR)
        hbuf[(i>>4)*HP + (i&15)] = h0[(size_t)(b0+(i&15))*HH + (i>>4)];
      for (int i = tid; i < AA*MB; i += NTHR)
        wbuf[i] = w_prev[(size_t)(b0+(i&15))*AA + (i>>4)];
    } else {
      const float* src = hws + ((t-1)&1)*(HH*MB);
      for (int i = tid; i < HH*MB; i += NTHR)
        hbuf[(i>>4)*HP + (i&15)] = gld(src + i);
    }
    __syncthreads();

    if (t > 0) {
      const int tp = t - 1;
      // p = h_tp @ Wp^T + bp  (30 x 16 dots of 400)
      if (tid < 3*KK*MB) {
        const int bb = tid & 15, j = tid >> 4;
        const float* wp = Wp + (size_t)j*HH;
        float s = bp[j];
        #pragma unroll 4
        for (int r = 0; r < HH; ++r) s += hbuf[r*HP+bb] * wp[r];
        pbuf[tid] = s;
      }
      __syncthreads();
      if (tid < KK*MB) {
        const int bb = tid & 15, i = tid >> 4;
        av[tid] = expf(pbuf[i*MB+bb]);
        bv[tid] = expf(pbuf[(KK+i)*MB+bb]);
        kbuf[tid] += expf(pbuf[(2*KK+i)*MB+bb]);
      }
      __syncthreads();
      { // phi
        const int bb = tid & 15, u = tid >> 4;
        for (int uu = u; uu <= SL; uu += 32) {
          float s = 0.f;
          #pragma unroll
          for (int i = 0; i < KK; ++i) {
            float d = kbuf[i*MB+bb] - (float)uu;
            s += av[i*MB+bb] * expf(-bv[i*MB+bb]*d*d);
          }
          s *= scalebuf[bb];
          phibuf[uu*MB+bb] = s;
          if (tp == TT-1 && wg == 0)
            out[O_PHI + (size_t)(b0+bb)*(SL+1) + uu] = s;
        }
      }
      __syncthreads();
      { // w_tp = phi[:, :L] @ onehots  -> wbuf; wg0 streams win_vec
        const int a = tid & 63, bq = tid >> 6;
        if (a < AA) {
          for (int bb = bq; bb < MB; bb += 8) {
            const float* oh = onehots + (size_t)(b0+bb)*(SL*AA) + a;
            float s = 0.f;
            #pragma unroll 4
            for (int l = 0; l < SL; ++l) s += phibuf[l*MB+bb] * oh[(size_t)l*AA];
            wbuf[a*MB+bb] = s;
            if (wg == 0) {
              __builtin_nontemporal_store(
                  s, out + O_WIN + (size_t)(b0+bb)*(TT*AA) + (size_t)tp*AA + a);
              if (tp == TT-1)
                out[O_WF + (size_t)(b0+bb)*AA + a] = s;
            }
          }
        }
      }
      { // hid1[tp] for this WG's unit slice, unit-major coalesced, NT
        const int j = tid & 31, bb = tid >> 5;
        if (j < UPW)
          __builtin_nontemporal_store(
              hbuf[(wg*UPW+j)*HP + bb],
              out + (size_t)(b0+bb)*(TT*HH) + (size_t)tp*HH + wg*UPW + j);
      }
      __syncthreads();
    }

    if (t < TT) {
      if (act) {
        float acc0=bias0, acc1=bias1, acc2=bias2, acc3=bias3;
        const float* xs = strks + (size_t)(b0+b)*(TT*3) + t*3;
        float x0 = xs[0], x1 = xs[1], x2 = xs[2];
        acc0 += x0*wip0[0]+x1*wip0[1]+x2*wip0[2];
        acc1 += x0*wip1[0]+x1*wip1[1]+x2*wip1[2];
        acc2 += x0*wip2[0]+x1*wip2[1]+x2*wip2[2];
        acc3 += x0*wip3[0]+x1*wip3[1]+x2*wip3[2];
        #pragma unroll 4
        for (int r = 0; r < HH; r += 4) {
          float hv0=hbuf[r*HP+b],     hv1=hbuf[(r+1)*HP+b],
                hv2=hbuf[(r+2)*HP+b], hv3=hbuf[(r+3)*HP+b];
          float4 w0=*(const float4*)(whp0+r), w1=*(const float4*)(whp1+r),
                 w2=*(const float4*)(whp2+r), w3=*(const float4*)(whp3+r);
          acc0 += hv0*w0.x+hv1*w0.y+hv2*w0.z+hv3*w0.w;
          acc1 += hv0*w1.x+hv1*w1.y+hv2*w1.z+hv3*w1.w;
          acc2 += hv0*w2.x+hv1*w2.y+hv2*w2.z+hv3*w2.w;
          acc3 += hv0*w3.x+hv1*w3.y+hv2*w3.z+hv3*w3.w;
        }
        #pragma unroll 4
        for (int k = 0; k < AA; ++k) {
          float wv = wbuf[k*MB+b];
          acc0 += wv*wip0[3+k]; acc1 += wv*wip1[3+k];
          acc2 += wv*wip2[3+k]; acc3 += wv*wip3[3+k];
        }
        float iv = 1.f/(1.f+expf(-acc0));
        float fv = 1.f/(1.f+expf(-acc1));
        float gv = tanhf(acc2);
        float ov = 1.f/(1.f+expf(-acc3));
        creg = fv*creg + iv*gv;
        float hv = ov*tanhf(creg);
        gst(hws + (t&1)*(HH*MB) + unit*MB + b, hv);
        if (t == TT-1) {
          out[O_HF + (size_t)(b0+b)*HH + unit] = hv;
          out[O_CF + (size_t)(b0+b)*HH + unit] = creg;
        }
      }
      __threadfence();
      __syncthreads();
      if (tid == 0) {
        __hip_atomic_fetch_add(cnt, 1, __ATOMIC_RELEASE, __HIP_MEMORY_SCOPE_AGENT);
        s_ok = spin_ge(cnt, NWG*(t+1));
      }
      __syncthreads();
      if (!s_ok) return;   // fail loudly, not a hang, if co-residency/sync breaks
    }
  }

  if (wg == 0 && tid < KK*MB)
    out[O_KF + (size_t)(b0+(tid&15))*KK + (tid>>4)] = kbuf[tid];
}

extern "C" void kernel_launch(void* const* d_in, const int* in_sizes, int n_in,
                              void* d_out, int out_size, void* d_ws, size_t ws_size,
                              hipStream_t stream) {
  const float* strks   = (const float*)d_in[0];
  const float* onehots = (const float*)d_in[1];
  const float* sents_m = (const float*)d_in[2];
  const float* w_prev  = (const float*)d_in[3];
  const float* k_prev  = (const float*)d_in[4];
  const float* h0      = (const float*)d_in[5];
  const float* c0      = (const float*)d_in[6];
  const float* W_ih    = (const float*)d_in[7];
  const float* b_ih    = (const float*)d_in[8];
  const float* W_hh    = (const float*)d_in[9];
  const float* b_hh    = (const float*)d_in[10];
  const float* Wp      = (const float*)d_in[11];
  const float* bp      = (const float*)d_in[12];
  float* out = (float*)d_out;
  float* ws  = (float*)d_ws;
  hipLaunchKernelGGL(init_ws, dim3(1), dim3(64), 0, stream, (int*)d_ws);
  hipLaunchKernelGGL(lstm_persist, dim3(NG*NWG), dim3(NTHR), 0, stream,
                     strks, onehots, sents_m, w_prev, k_prev, h0, c0,
                     W_ih, b_ih, W_hh, b_hh, Wp, bp, out, ws);
}

// Round 3
// 46286.490 us; speedup vs baseline: 1.0630x; 1.0630x over previous
//
#include <hip/hip_runtime.h>
#include <hip/hip_bf16.h>
#include <math.h>

#define BATCH 128
#define TT 800
#define SL 64
#define AA 60
#define HH 400
#define KK 10
#define MB 16
#define NG 8
#define NTHR 512
#define NTILE_P 104     // 100 real unit-gate tiles + 4 dummy (uniform 13/wave)
#define NKT 15          // K tiles: K=480 = [x:3|w:60|0:1|h:400|0:16]
#define AST 488         // Abuf row stride (bf16): 480 + 8 pad (stride%32dw==20)
#define HST 424         // hstage row stride (bf16): 416 + 8 pad

#define O_HF   (BATCH*TT*HH)
#define O_CF   (O_HF + BATCH*HH)
#define O_WIN  (O_CF + BATCH*HH)
#define O_WF   (O_WIN + BATCH*TT*AA)
#define O_KF   (O_WF + BATCH*AA)
#define O_PHI  (O_KF + BATCH*KK)

#define WPACK_SHORTS (NTILE_P*NKT*64*8)
#define PPACK_SHORTS (2*13*64*8)

typedef __attribute__((ext_vector_type(8))) short bf16x8;
typedef __attribute__((ext_vector_type(4))) float f32x4;

// ---------------- prep: pack weights into MFMA B-fragment order (bf16) ------
// Wpack[t][kt][lane][8]: B[k=kt*32+(l>>4)*8+j][n=l&15], n->(gate=n>>2, du=n&3),
// unit u=4t+du, W row = gate*HH+u; k<63:W_ih col k; k==63:0; 64<=k<464:W_hh; else 0.
__global__ void prep_pack(const float* __restrict__ W_ih, const float* __restrict__ W_hh,
                          const float* __restrict__ Wp, __hip_bfloat16* __restrict__ dst) {
  int tid = blockIdx.x*256 + threadIdx.x;
  const int NWT = NTILE_P*NKT*64;
  if (tid < NWT) {
    int l = tid & 63;
    int kt = (tid >> 6) % NKT;
    int t  = (tid >> 6) / NKT;
    int nn = l & 15;
    int gt = nn >> 2, du = nn & 3;
    int u = t*4 + du;
    int kb = kt*32 + (l>>4)*8;
    __align__(16) short v[8];
    #pragma unroll
    for (int j = 0; j < 8; ++j) {
      int k = kb + j;
      float x = 0.f;
      if (u < HH) {
        if (k < 63) x = W_ih[(size_t)(gt*HH+u)*63 + k];
        else if (k >= 64 && k < 464) x = W_hh[(size_t)(gt*HH+u)*HH + (k-64)];
      }
      __hip_bfloat16 hb = __float2bfloat16(x);
      v[j] = *reinterpret_cast<short*>(&hb);
    }
    *(bf16x8*)(dst + (size_t)tid*8) = *(const bf16x8*)v;
  } else if (tid < NWT + 2*13*64) {
    int r = tid - NWT;
    int l = r & 63;
    int kt = (r >> 6) % 13;
    int tp = (r >> 6) / 13;
    int jj = tp*16 + (l&15);
    int kb = (kt+2)*32 + (l>>4)*8;   // k in [64,480): h region
    __align__(16) short v[8];
    #pragma unroll
    for (int j = 0; j < 8; ++j) {
      int k = kb + j;
      float x = (jj < 30 && k >= 64 && k < 464) ? Wp[(size_t)jj*HH + (k-64)] : 0.f;
      __hip_bfloat16 hb = __float2bfloat16(x);
      v[j] = *reinterpret_cast<short*>(&hb);
    }
    *(bf16x8*)(dst + (size_t)WPACK_SHORTS + (size_t)r*8) = *(const bf16x8*)v;
  }
}

// ---------------- main: one WG per 16-batch group, zero inter-WG traffic ----
__global__ __launch_bounds__(NTHR, 2) void lstm_mfma(
    const float* __restrict__ strks, const float* __restrict__ onehots,
    const float* __restrict__ sents_m, const float* __restrict__ w_prev,
    const float* __restrict__ k_prev, const float* __restrict__ h0,
    const float* __restrict__ c0, const float* __restrict__ b_ih,
    const float* __restrict__ b_hh, const float* __restrict__ bp,
    const __hip_bfloat16* __restrict__ pk, float* __restrict__ out)
{
  const int g = blockIdx.x;
  const int b0 = g * MB;
  const int tid = threadIdx.x;
  const int lane = tid & 63;
  const int wid = tid >> 6;

  __shared__ __align__(16) __hip_bfloat16 Abuf[MB*AST];    // [b][k] gate A-operand
  __shared__ __align__(16) __hip_bfloat16 hstage[MB*HST];  // [b][u] fresh h_t
  __shared__ float pbuf[32*MB];
  __shared__ float phib[(SL+1)*MB];
  __shared__ float avb[KK*MB], bvb[KK*MB], kvb[KK*MB];
  __shared__ float scaleb[MB];

  const int t0 = wid * 13;            // 13 tiles per wave (4 dummies total)
  const int nn = lane & 15;           // B/D col
  const int gt = nn >> 2, du = nn & 3;
  const bool gt2 = (gt == 2);
  const int bq = lane >> 4;           // D rows = 4*bq + r

  // biases + c-state (dummy tiles u>=400 -> 0)
  float bias[13], cst[13][4];
  #pragma unroll
  for (int i = 0; i < 13; ++i) {
    int u = (t0+i)*4 + du;
    bias[i] = (u < HH) ? (b_ih[gt*HH+u] + b_hh[gt*HH+u]) : 0.f;
    #pragma unroll
    for (int r = 0; r < 4; ++r)
      cst[i][r] = (u < HH) ? c0[(size_t)(b0+4*bq+r)*HH + u] : 0.f;
  }
  float pbias = 0.f;
  if (wid < 2) { int jj = wid*16 + nn; if (jj < 30) pbias = bp[jj]; }

  // prologue: Abuf = [x_0 | w_prev | 0 | h0 | 0], hstage pad zero, k-state, scale
  for (int i = tid; i < MB*AST; i += NTHR) {
    int b = i / AST, k = i % AST;
    float v = 0.f;
    if (k < 3) v = strks[(size_t)(b0+b)*(TT*3) + k];
    else if (k < 63) v = w_prev[(size_t)(b0+b)*AA + (k-3)];
    else if (k >= 64 && k < 464) v = h0[(size_t)(b0+b)*HH + (k-64)];
    Abuf[i] = __float2bfloat16(v);
  }
  for (int i = tid; i < MB*HST; i += NTHR) hstage[i] = __float2bfloat16(0.f);
  for (int i = tid; i < KK*MB; i += NTHR)
    kvb[(i>>4)*MB + (i&15)] = k_prev[(size_t)(b0+(i&15))*KK + (i>>4)];
  if (tid < MB) {
    float s = 0.f;
    for (int l = 0; l < SL; ++l) s += sents_m[(size_t)(b0+tid)*SL + l];
    scaleb[tid] = (float)SL / s;
  }
  __syncthreads();

  const __hip_bfloat16* ppk = pk + WPACK_SHORTS;
  const __hip_bfloat16* arow = Abuf + (size_t)nn*AST + bq*8;   // A row = batch = lane&15
  const __hip_bfloat16* wl = pk + ((size_t)(t0*NKT)*64 + lane)*8;

#define POSTPROC(ACC, I) do {                                                  \
    float vv[4];                                                               \
    _Pragma("unroll") for (int r = 0; r < 4; ++r) {                            \
      float v = (ACC)[r];                                                      \
      float sg = 1.f/(1.f + __expf(gt2 ? -2.f*v : -v));                        \
      vv[r] = gt2 ? 2.f*sg - 1.f : sg;                                         \
    }                                                                          \
    _Pragma("unroll") for (int r = 0; r < 4; ++r) {                            \
      float v = vv[r];                                                         \
      float x4 = __shfl_xor(v, 4), x8 = __shfl_xor(v, 8), x12 = __shfl_xor(v, 12); \
      float iv = (gt==0)?v  :(gt==1)?x4 :(gt==2)?x8 :x12;                      \
      float fv = (gt==0)?x4 :(gt==1)?v  :(gt==2)?x12:x8;                       \
      float gv = (gt==0)?x8 :(gt==1)?x12:(gt==2)?v  :x4;                       \
      float ov = (gt==0)?x12:(gt==1)?x8 :(gt==2)?x4 :v;                        \
      float c = fv*cst[I][r] + iv*gv;                                          \
      cst[I][r] = c;                                                           \
      float hv = ov * (2.f/(1.f + __expf(-2.f*c)) - 1.f);                      \
      if (gt == 0) {                                                           \
        int u = (t0+(I))*4 + du;                                               \
        if (u < HH) {                                                          \
          hstage[(4*bq+r)*HST + u] = __float2bfloat16(hv);                     \
          if (t == TT-1) {                                                     \
            out[O_HF + (size_t)(b0+4*bq+r)*HH + u] = hv;                       \
            out[O_CF + (size_t)(b0+4*bq+r)*HH + u] = c;                        \
          }                                                                    \
        }                                                                      \
      }                                                                        \
    }                                                                          \
  } while (0)

  for (int t = 0; t < TT; ++t) {
    // ---- P0: gates via MFMA (reads Abuf = x_t|w_{t-1}|h_{t-1}; writes hstage)
    #pragma unroll
    for (int pr = 0; pr < 7; ++pr) {
      const int i0 = 2*pr, i1 = 2*pr + 1;
      f32x4 a0 = {bias[i0], bias[i0], bias[i0], bias[i0]};
      f32x4 a1 = {0.f, 0.f, 0.f, 0.f};
      if (i1 < 13) a1 = (f32x4){bias[i1], bias[i1], bias[i1], bias[i1]};
      #pragma unroll
      for (int kt = 0; kt < NKT; ++kt) {
        bf16x8 af = *(const bf16x8*)(arow + kt*32);
        bf16x8 w0 = *(const bf16x8*)(wl + (size_t)(i0*NKT + kt)*512);
        a0 = __builtin_amdgcn_mfma_f32_16x16x32_bf16(af, w0, a0, 0, 0, 0);
        if (i1 < 13) {
          bf16x8 w1 = *(const bf16x8*)(wl + (size_t)(i1*NKT + kt)*512);
          a1 = __builtin_amdgcn_mfma_f32_16x16x32_bf16(af, w1, a1, 0, 0, 0);
        }
      }
      POSTPROC(a0, i0);
      if (i1 < 13) POSTPROC(a1, i1);
    }
    __syncthreads();

    // ---- P2: waves 0-1: p = h_t @ Wp^T (MFMA); waves 2-7: hid1 + hstage->Abuf
    if (wid < 2) {
      const __hip_bfloat16* prow = hstage + (size_t)nn*HST + bq*8;
      const __hip_bfloat16* pwl = ppk + ((size_t)(wid*13)*64 + lane)*8;
      f32x4 pa = {pbias, pbias, pbias, pbias};
      #pragma unroll
      for (int kt = 0; kt < 13; ++kt) {
        bf16x8 af = *(const bf16x8*)(prow + kt*32);
        bf16x8 w  = *(const bf16x8*)(pwl + (size_t)kt*512);
        pa = __builtin_amdgcn_mfma_f32_16x16x32_bf16(af, w, pa, 0, 0, 0);
      }
      int jj = wid*16 + nn;
      if (jj < 30) {
        #pragma unroll
        for (int r = 0; r < 4; ++r) pbuf[jj*MB + 4*bq + r] = pa[r];
      }
    } else {
      for (int idx = tid - 128; idx < HH*MB; idx += 384) {
        int b = idx / HH, u = idx % HH;
        __hip_bfloat16 hb = hstage[b*HST + u];
        Abuf[b*AST + 64 + u] = hb;
        __builtin_nontemporal_store(__bfloat162float(hb),
            out + (size_t)(b0+b)*(TT*HH) + (size_t)t*HH + u);
      }
    }
    __syncthreads();

    // ---- P3: a,b,k update
    if (tid < KK*MB) {
      int b = tid & 15, j = tid >> 4;
      avb[j*MB+b] = __expf(pbuf[j*MB+b]);
      bvb[j*MB+b] = __expf(pbuf[(10+j)*MB+b]);
      kvb[j*MB+b] += __expf(pbuf[(20+j)*MB+b]);
    }
    __syncthreads();

    // ---- P4: phi
    {
      int b = tid & 15, u0 = tid >> 4;
      for (int uu = u0; uu <= SL; uu += 32) {
        float s = 0.f;
        #pragma unroll
        for (int j = 0; j < KK; ++j) {
          float d = kvb[j*MB+b] - (float)uu;
          s += avb[j*MB+b] * __expf(-bvb[j*MB+b]*d*d);
        }
        s *= scaleb[b];
        phib[uu*MB+b] = s;
        if (t == TT-1) out[O_PHI + (size_t)(b0+b)*(SL+1) + uu] = s;
      }
    }
    __syncthreads();

    // ---- P5: w einsum -> Abuf + win_vec; stage x_{t+1}
    for (int i = tid; i < BATCH*0 + MB*AA; i += NTHR) {   // 960 outputs
      int b = i / AA, a = i % AA;
      const float* oh = onehots + (size_t)(b0+b)*(SL*AA) + a;
      float s = 0.f;
      #pragma unroll 8
      for (int l = 0; l < SL; ++l) s += phib[l*MB+b] * oh[(size_t)l*AA];
      __builtin_nontemporal_store(s,
          out + O_WIN + (size_t)(b0+b)*(TT*AA) + (size_t)t*AA + a);
      if (t == TT-1) out[O_WF + (size_t)(b0+b)*AA + a] = s;
      Abuf[b*AST + 3 + a] = __float2bfloat16(s);
    }
    if (t + 1 < TT && tid >= 464 && tid < 464 + MB*3) {
      int idx = tid - 464;
      int b = idx / 3, c = idx % 3;
      Abuf[b*AST + c] = __float2bfloat16(
          strks[(size_t)(b0+b)*(TT*3) + (size_t)(t+1)*3 + c]);
    }
    __syncthreads();
  }

  if (tid < KK*MB)
    out[O_KF + (size_t)(b0+(tid&15))*KK + (tid>>4)] = kvb[(tid>>4)*MB + (tid&15)];
#undef POSTPROC
}

extern "C" void kernel_launch(void* const* d_in, const int* in_sizes, int n_in,
                              void* d_out, int out_size, void* d_ws, size_t ws_size,
                              hipStream_t stream) {
  const float* strks   = (const float*)d_in[0];
  const float* onehots = (const float*)d_in[1];
  const float* sents_m = (const float*)d_in[2];
  const float* w_prev  = (const float*)d_in[3];
  const float* k_prev  = (const float*)d_in[4];
  const float* h0      = (const float*)d_in[5];
  const float* c0      = (const float*)d_in[6];
  const float* W_ih    = (const float*)d_in[7];
  const float* b_ih    = (const float*)d_in[8];
  const float* W_hh    = (const float*)d_in[9];
  const float* b_hh    = (const float*)d_in[10];
  const float* Wp      = (const float*)d_in[11];
  const float* bp      = (const float*)d_in[12];
  float* out = (float*)d_out;
  __hip_bfloat16* pk = (__hip_bfloat16*)d_ws;   // needs ~1.63 MB

  int prep_threads = NTILE_P*NKT*64 + 2*13*64;
  hipLaunchKernelGGL(prep_pack, dim3((prep_threads + 255)/256), dim3(256), 0, stream,
                     W_ih, W_hh, Wp, pk);
  hipLaunchKernelGGL(lstm_mfma, dim3(NG), dim3(NTHR), 0, stream,
                     strks, onehots, sents_m, w_prev, k_prev, h0, c0,
                     b_ih, b_hh, bp, pk, out);
}

// Round 4
// 22843.291 us; speedup vs baseline: 2.1538x; 2.0263x over previous
//
#include <hip/hip_runtime.h>
#include <hip/hip_bf16.h>
#include <math.h>

#define BATCH 128
#define TT 800
#define SL 64
#define AA 60
#define HH 400
#define KK 10
#define MB 16
#define NG 8
#define NWG 16          // WGs per group, one CU each
#define NTHR 512
#define TPW 7           // gate tiles per WG (one per wave, waves 0..6)
#define NTILE (NWG*TPW) // 112 (tiles >=100 are zero-padded dummies)
#define NKT 15          // K tiles: K=480 = [x:3|w:60|0:1|h:400|0:16]
#define AST 488         // Abuf row stride (bf16)
#define NPF 26          // Wp fragments (2 n-tiles x 13 k-tiles)

#define O_HF   (BATCH*TT*HH)
#define O_CF   (O_HF + BATCH*HH)
#define O_WIN  (O_CF + BATCH*HH)
#define O_WF   (O_WIN + BATCH*TT*AA)
#define O_KF   (O_WF + BATCH*AA)
#define O_PHI  (O_KF + BATCH*KK)

// ws layout: cnt [TT*NG] ints | hws [2][NG][HH][MB] floats | gate pack | Wp pack
#define CNT_N (TT*NG)                   // 6400 ints
#define HWS_F CNT_N                     // float offset 6400
#define HWS_N (2*NG*HH*MB)              // 102400 floats
#define PK_S  ((CNT_N + HWS_N)*2)       // short offset 217600
#define GATE_FRAGS (NTILE*NKT)          // 1680 fragments x 512 shorts
#define PPK_S (PK_S + GATE_FRAGS*512)

typedef __attribute__((ext_vector_type(8))) short bf16x8;
typedef __attribute__((ext_vector_type(4))) float f32x4;

__global__ void zero_cnt(int* c) {
  int i = blockIdx.x*256 + threadIdx.x;
  if (i < CNT_N) c[i] = 0;
}

// pack weights into MFMA B-fragment order, bf16
__global__ void prep_pack(const float* __restrict__ W_ih, const float* __restrict__ W_hh,
                          const float* __restrict__ Wp, short* __restrict__ dst) {
  int tid = blockIdx.x*256 + threadIdx.x;
  const int NWT = GATE_FRAGS*64;
  if (tid < NWT) {
    int l = tid & 63;
    int kt = (tid >> 6) % NKT;
    int tt = (tid >> 6) / NKT;
    int nn = l & 15;
    int gt = nn >> 2, du = nn & 3;
    int u = tt*4 + du;
    int kb = kt*32 + (l>>4)*8;
    __align__(16) short v[8];
    #pragma unroll
    for (int j = 0; j < 8; ++j) {
      int k = kb + j;
      float x = 0.f;
      if (u < HH) {
        if (k < 63) x = W_ih[(size_t)(gt*HH+u)*63 + k];
        else if (k >= 64 && k < 464) x = W_hh[(size_t)(gt*HH+u)*HH + (k-64)];
      }
      __hip_bfloat16 hb = __float2bfloat16(x);
      v[j] = *reinterpret_cast<short*>(&hb);
    }
    *(bf16x8*)(dst + (size_t)PK_S + (size_t)tid*8) = *(const bf16x8*)v;
  } else if (tid < NWT + NPF*64) {
    int r = tid - NWT;
    int l = r & 63;
    int idx = r >> 6;            // tp*13 + kt
    int kt = idx % 13;
    int tp = idx / 13;
    int jj = tp*16 + (l&15);
    int kb = (kt+2)*32 + (l>>4)*8;   // h region k in [64,480)
    __align__(16) short v[8];
    #pragma unroll
    for (int j = 0; j < 8; ++j) {
      int k = kb + j;
      float x = (jj < 3*KK && k >= 64 && k < 464) ? Wp[(size_t)jj*HH + (k-64)] : 0.f;
      __hip_bfloat16 hb = __float2bfloat16(x);
      v[j] = *reinterpret_cast<short*>(&hb);
    }
    *(bf16x8*)(dst + (size_t)PPK_S + (size_t)r*8) = *(const bf16x8*)v;
  }
}

__global__ __launch_bounds__(NTHR, 1) void lstm_split(
    const float* __restrict__ strks, const float* __restrict__ onehots,
    const float* __restrict__ sents_m, const float* __restrict__ w_prev,
    const float* __restrict__ k_prev, const float* __restrict__ h0,
    const float* __restrict__ c0, const float* __restrict__ b_ih,
    const float* __restrict__ b_hh, const float* __restrict__ bp,
    float* __restrict__ out, float* __restrict__ ws)
{
  const int g  = blockIdx.x >> 4;
  const int wg = blockIdx.x & 15;
  const int b0 = g*MB;
  const int tid = threadIdx.x;
  const int lane = tid & 63;
  const int wid = tid >> 6;
  const int nn = lane & 15, gt = nn >> 2, du = nn & 3, bq = lane >> 4;

  int* cnt = (int*)ws;
  float* hws = ws + HWS_F;
  const __hip_bfloat16* gpk  = (const __hip_bfloat16*)((const short*)ws + PK_S);
  const __hip_bfloat16* gppk = (const __hip_bfloat16*)((const short*)ws + PPK_S);

  __shared__ __align__(16) __hip_bfloat16 Abuf[MB*AST];  // [b][k]
  __shared__ float phib[(SL+1)*MB];
  __shared__ float avb[KK*MB], bvb[KK*MB], kvb[KK*MB];
  __shared__ float scaleb[MB];
  __shared__ int s_ok;

  const int tt = wg*TPW + wid;                      // gate tile (wid<7)
  const int u  = (wid < TPW) ? (tt*4 + du) : HH;
  const bool gate_act = (wid < TPW) && (u < HH);

  float bias = 0.f, cst[4] = {0.f,0.f,0.f,0.f};
  if (gate_act) {
    bias = b_ih[gt*HH+u] + b_hh[gt*HH+u];
    #pragma unroll
    for (int r = 0; r < 4; ++r) cst[r] = c0[(size_t)(b0+4*bq+r)*HH + u];
  }
  float pbias0 = 0.f, pbias1 = 0.f;
  if (wid == 7) {
    if (nn < 3*KK - 16) pbias1 = bp[16 + nn];
    pbias0 = bp[nn];                                 // nn<16 always < 30
  }

  // weights -> registers, once
  bf16x8 wreg[NKT];
  if (wid < TPW) {
    const __hip_bfloat16* base = gpk + ((size_t)tt*NKT*64 + lane)*8;
    #pragma unroll
    for (int kt = 0; kt < NKT; ++kt) wreg[kt] = *(const bf16x8*)(base + (size_t)kt*512);
  }
  bf16x8 preg[NPF];
  if (wid == 7) {
    const __hip_bfloat16* base = gppk + (size_t)lane*8;
    #pragma unroll
    for (int i = 0; i < NPF; ++i) preg[i] = *(const bf16x8*)(base + (size_t)i*512);
  }

  // Abuf = [x_0 | w_prev | 0 | h0 | 0]
  for (int i = tid; i < MB*AST; i += NTHR) {
    int b = i / AST, k = i % AST;
    float v = 0.f;
    if (k < 3) v = strks[(size_t)(b0+b)*(TT*3) + k];
    else if (k < 63) v = w_prev[(size_t)(b0+b)*AA + (k-3)];
    else if (k >= 64 && k < 464) v = h0[(size_t)(b0+b)*HH + (k-64)];
    Abuf[i] = __float2bfloat16(v);
  }
  for (int i = tid; i < KK*MB; i += NTHR)
    kvb[(i>>4)*MB + (i&15)] = k_prev[(size_t)(b0+(i&15))*KK + (i>>4)];
  if (tid < MB) {
    float s = 0.f;
    for (int l = 0; l < SL; ++l) s += sents_m[(size_t)(b0+tid)*SL + l];
    scaleb[tid] = (float)SL / s;
  }
  __syncthreads();

  const bool OUTW = (wg == NWG-1);   // wg15 has only dummy gate tiles -> output writer

  for (int t = 0; t < TT; ++t) {
    float* hpub = hws + (size_t)((t&1)*NG + g)*(HH*MB);

    // ---- P1: gate MFMA + activations + publish h_t
    if (wid < TPW) {
      const __hip_bfloat16* arow = Abuf + nn*AST + bq*8;
      f32x4 acc = {bias,bias,bias,bias};
      #pragma unroll
      for (int kt = 0; kt < NKT; ++kt) {
        bf16x8 af = *(const bf16x8*)(arow + kt*32);
        acc = __builtin_amdgcn_mfma_f32_16x16x32_bf16(af, wreg[kt], acc, 0, 0, 0);
      }
      float vv[4];
      #pragma unroll
      for (int r = 0; r < 4; ++r) {
        float v = acc[r];
        float sg = 1.f/(1.f + __expf(gt==2 ? -2.f*v : -v));
        vv[r] = (gt==2) ? 2.f*sg - 1.f : sg;
      }
      #pragma unroll
      for (int r = 0; r < 4; ++r) {
        float v = vv[r];
        float x4 = __shfl_xor(v,4), x8 = __shfl_xor(v,8), x12 = __shfl_xor(v,12);
        float iv = (gt==0)?v  :(gt==1)?x4 :(gt==2)?x8 :x12;
        float fv = (gt==0)?x4 :(gt==1)?v  :(gt==2)?x12:x8;
        float gv = (gt==0)?x8 :(gt==1)?x12:(gt==2)?v  :x4;
        float ov = (gt==0)?x12:(gt==1)?x8 :(gt==2)?x4 :v;
        float c = fv*cst[r] + iv*gv;
        cst[r] = c;
        float hv = ov * (2.f/(1.f + __expf(-2.f*c)) - 1.f);
        if (gate_act && gt == 0) {
          int bb = 4*bq + r;
          __hip_atomic_store(hpub + u*MB + bb, hv, __ATOMIC_RELAXED, __HIP_MEMORY_SCOPE_AGENT);
          __builtin_nontemporal_store(hv,
              out + (size_t)(b0+bb)*(TT*HH) + (size_t)t*HH + u);
          if (t == TT-1) {
            out[O_HF + (size_t)(b0+bb)*HH + u] = hv;
            out[O_CF + (size_t)(b0+bb)*HH + u] = c;
          }
        }
      }
    }
    __syncthreads();   // each wave drains its vmcnt before the barrier

    // ---- P2: group barrier via LLC counter (no acquire anywhere)
    if (tid == 0) {
      int* cp = cnt + t*NG + g;
      __hip_atomic_fetch_add(cp, 1, __ATOMIC_RELEASE, __HIP_MEMORY_SCOPE_AGENT);
      int ok = 0;
      for (int it = 0; it < (1<<17); ++it) {
        if (__hip_atomic_load(cp, __ATOMIC_RELAXED, __HIP_MEMORY_SCOPE_AGENT) >= NWG) { ok = 1; break; }
        __builtin_amdgcn_s_sleep(1);
      }
      s_ok = ok;
    }
    __syncthreads();
    if (!s_ok) return;   // loud failure, not a hang

    // ---- P3: read full h_t -> Abuf (bf16); stage x_{t+1}
    for (int i = tid; i < HH*MB; i += NTHR) {
      float v = __hip_atomic_load(hpub + i, __ATOMIC_RELAXED, __HIP_MEMORY_SCOPE_AGENT);
      Abuf[(i & 15)*AST + 64 + (i >> 4)] = __float2bfloat16(v);
    }
    if (t+1 < TT && tid < MB*3) {
      int b = tid/3, cc = tid%3;
      Abuf[b*AST + cc] = __float2bfloat16(
          strks[(size_t)(b0+b)*(TT*3) + (size_t)(t+1)*3 + cc]);
    }
    __syncthreads();

    // ---- P4: wave 7: p = h_t @ Wp^T via MFMA; a,b,k update
    if (wid == 7) {
      const __hip_bfloat16* prow = Abuf + nn*AST + 64 + bq*8;
      f32x4 pa0 = {pbias0,pbias0,pbias0,pbias0};
      f32x4 pa1 = {pbias1,pbias1,pbias1,pbias1};
      #pragma unroll
      for (int kt = 0; kt < 13; ++kt) {
        bf16x8 af = *(const bf16x8*)(prow + kt*32);
        pa0 = __builtin_amdgcn_mfma_f32_16x16x32_bf16(af, preg[kt],    pa0, 0, 0, 0);
        pa1 = __builtin_amdgcn_mfma_f32_16x16x32_bf16(af, preg[13+kt], pa1, 0, 0, 0);
      }
      #pragma unroll
      for (int tp = 0; tp < 2; ++tp) {
        f32x4 pa = tp ? pa1 : pa0;
        int jj = tp*16 + nn;
        if (jj < 3*KK) {
          #pragma unroll
          for (int r = 0; r < 4; ++r) {
            float e = __expf(pa[r]);
            int row = 4*bq + r;
            if (jj < KK) avb[jj*MB + row] = e;
            else if (jj < 2*KK) bvb[(jj-KK)*MB + row] = e;
            else kvb[(jj-2*KK)*MB + row] += e;
          }
        }
      }
    }
    __syncthreads();

    // ---- P6: phi
    {
      int b = tid & 15, u0 = tid >> 4;
      for (int uu = u0; uu <= SL; uu += 32) {
        float s = 0.f;
        #pragma unroll
        for (int j = 0; j < KK; ++j) {
          float d = kvb[j*MB+b] - (float)uu;
          s += avb[j*MB+b] * __expf(-bvb[j*MB+b]*d*d);
        }
        s *= scaleb[b];
        phib[uu*MB+b] = s;
        if (t == TT-1 && OUTW) out[O_PHI + (size_t)(b0+b)*(SL+1) + uu] = s;
      }
    }
    __syncthreads();

    // ---- P7: w_t einsum -> Abuf w cols (+ outputs from wg15)
    for (int i = tid; i < MB*AA; i += NTHR) {
      int b = i / AA, a = i % AA;
      const float* oh = onehots + (size_t)(b0+b)*(SL*AA) + a;
      float s = 0.f;
      #pragma unroll 8
      for (int l = 0; l < SL; ++l) s += phib[l*MB+b] * oh[(size_t)l*AA];
      Abuf[b*AST + 3 + a] = __float2bfloat16(s);
      if (OUTW) {
        __builtin_nontemporal_store(s,
            out + O_WIN + (size_t)(b0+b)*(TT*AA) + (size_t)t*AA + a);
        if (t == TT-1) out[O_WF + (size_t)(b0+b)*AA + a] = s;
      }
    }
    __syncthreads();
  }

  if (OUTW && tid < KK*MB)
    out[O_KF + (size_t)(b0+(tid&15))*KK + (tid>>4)] = kvb[(tid>>4)*MB + (tid&15)];
}

extern "C" void kernel_launch(void* const* d_in, const int* in_sizes, int n_in,
                              void* d_out, int out_size, void* d_ws, size_t ws_size,
                              hipStream_t stream) {
  const float* strks   = (const float*)d_in[0];
  const float* onehots = (const float*)d_in[1];
  const float* sents_m = (const float*)d_in[2];
  const float* w_prev  = (const float*)d_in[3];
  const float* k_prev  = (const float*)d_in[4];
  const float* h0      = (const float*)d_in[5];
  const float* c0      = (const float*)d_in[6];
  const float* W_ih    = (const float*)d_in[7];
  const float* b_ih    = (const float*)d_in[8];
  const float* W_hh    = (const float*)d_in[9];
  const float* b_hh    = (const float*)d_in[10];
  const float* Wp      = (const float*)d_in[11];
  const float* bp      = (const float*)d_in[12];

  hipLaunchKernelGGL(zero_cnt, dim3((CNT_N+255)/256), dim3(256), 0, stream, (int*)d_ws);
  int prep_threads = GATE_FRAGS*64 + NPF*64;
  hipLaunchKernelGGL(prep_pack, dim3((prep_threads+255)/256), dim3(256), 0, stream,
                     W_ih, W_hh, Wp, (short*)d_ws);
  hipLaunchKernelGGL(lstm_split, dim3(NG*NWG), dim3(NTHR), 0, stream,
                     strks, onehots, sents_m, w_prev, k_prev, h0, c0,
                     b_ih, b_hh, bp, (float*)d_out, (float*)d_ws);
}

// Round 5
// 15743.127 us; speedup vs baseline: 3.1252x; 1.4510x over previous
//
#include <hip/hip_runtime.h>
#include <hip/hip_bf16.h>
#include <math.h>

#define BATCH 128
#define TT 800
#define SL 64
#define AA 60
#define HH 400
#define KK 10
#define MB 16
#define NG 8
#define NWG 16          // WGs per group
#define NTHR 512
#define TPW 7           // gate tiles per WG (waves 0..6)
#define NTILE (NWG*TPW) // 112 tiles (>=100 dummy)
#define NKT 15          // K tiles: K=480 = [x:3|w:60|0:1|h:400|0:16]
#define AST 488         // Abuf row stride (bf16)
#define NPF 26          // Wp fragments
#define UPW 28          // unit slots per WG (real if <400)

#define O_HF   (BATCH*TT*HH)
#define O_CF   (O_HF + BATCH*HH)
#define O_WIN  (O_CF + BATCH*HH)
#define O_WF   (O_WIN + BATCH*TT*AA)
#define O_KF   (O_WF + BATCH*AA)
#define O_PHI  (O_KF + BATCH*KK)

// ws: cnt slots [NG*NWG][16] ints | hws [2][NG][MB][HH] fp32 | gate pack | Wp pack
#define CNT_N (NG*NWG*16)               // 2048 ints (64B-strided slots)
#define HWS_F CNT_N
#define HWS_N (2*NG*MB*HH)              // 102400 floats
#define PK_S  ((CNT_N + HWS_N)*2)       // short offset
#define GATE_FRAGS (NTILE*NKT)          // 1680
#define PPK_S (PK_S + GATE_FRAGS*512)

typedef __attribute__((ext_vector_type(8))) short bf16x8;
typedef __attribute__((ext_vector_type(4))) float f32x4;

__global__ void zero_cnt(int* c) {
  int i = blockIdx.x*256 + threadIdx.x;
  if (i < CNT_N) c[i] = 0;
}

__global__ void prep_pack(const float* __restrict__ W_ih, const float* __restrict__ W_hh,
                          const float* __restrict__ Wp, short* __restrict__ dst) {
  int tid = blockIdx.x*256 + threadIdx.x;
  const int NWT = GATE_FRAGS*64;
  if (tid < NWT) {
    int l = tid & 63;
    int kt = (tid >> 6) % NKT;
    int tt = (tid >> 6) / NKT;
    int nn = l & 15;
    int gt = nn >> 2, du = nn & 3;
    int u = tt*4 + du;
    int kb = kt*32 + (l>>4)*8;
    __align__(16) short v[8];
    #pragma unroll
    for (int j = 0; j < 8; ++j) {
      int k = kb + j;
      float x = 0.f;
      if (u < HH) {
        if (k < 63) x = W_ih[(size_t)(gt*HH+u)*63 + k];
        else if (k >= 64 && k < 464) x = W_hh[(size_t)(gt*HH+u)*HH + (k-64)];
      }
      __hip_bfloat16 hb = __float2bfloat16(x);
      v[j] = *reinterpret_cast<short*>(&hb);
    }
    *(bf16x8*)(dst + (size_t)PK_S + (size_t)tid*8) = *(const bf16x8*)v;
  } else if (tid < NWT + NPF*64) {
    int r = tid - NWT;
    int l = r & 63;
    int idx = r >> 6;
    int kt = idx % 13;
    int tp = idx / 13;
    int jj = tp*16 + (l&15);
    int kb = (kt+2)*32 + (l>>4)*8;
    __align__(16) short v[8];
    #pragma unroll
    for (int j = 0; j < 8; ++j) {
      int k = kb + j;
      float x = (jj < 3*KK && k >= 64 && k < 464) ? Wp[(size_t)jj*HH + (k-64)] : 0.f;
      __hip_bfloat16 hb = __float2bfloat16(x);
      v[j] = *reinterpret_cast<short*>(&hb);
    }
    *(bf16x8*)(dst + (size_t)PPK_S + (size_t)r*8) = *(const bf16x8*)v;
  }
}

__global__ __launch_bounds__(NTHR, 1) void lstm_split(
    const float* __restrict__ strks, const float* __restrict__ onehots,
    const float* __restrict__ sents_m, const float* __restrict__ w_prev,
    const float* __restrict__ k_prev, const float* __restrict__ h0,
    const float* __restrict__ c0, const float* __restrict__ b_ih,
    const float* __restrict__ b_hh, const float* __restrict__ bp,
    float* __restrict__ out, float* __restrict__ ws)
{
  const int g  = blockIdx.x >> 4;
  const int wg = blockIdx.x & 15;
  const int b0 = g*MB;
  const int tid = threadIdx.x;
  const int lane = tid & 63;
  const int wid = tid >> 6;
  const int nn = lane & 15, gt = nn >> 2, du = nn & 3, bq = lane >> 4;

  int* cnt = (int*)ws;
  int* myslot = cnt + (g*NWG + wg)*16;
  float* hws = ws + HWS_F;
  const __hip_bfloat16* gpk  = (const __hip_bfloat16*)((const short*)ws + PK_S);
  const __hip_bfloat16* gppk = (const __hip_bfloat16*)((const short*)ws + PPK_S);

  __shared__ __align__(16) __hip_bfloat16 Abuf[MB*AST];  // [b][k]
  __shared__ float hstage[MB*UPW];     // [b][u_loc] fp32
  __shared__ float pbuf[30*MB];        // [j][b]
  __shared__ float phib[MB*66];        // [b][u]
  __shared__ float avb[KK*MB], bvb[KK*MB], kvb[KK*MB];   // [j][b]
  __shared__ float scaleb[MB];
  __shared__ int s_ok;

  const int tt = wg*TPW + wid;
  const int u  = (wid < TPW) ? (tt*4 + du) : HH;
  const bool gate_act = (wid < TPW) && (u < HH);
  const bool OUTW = (wg == NWG-1);     // all-dummy gate tiles -> output writer

  float bias = 0.f, cst[4] = {0.f,0.f,0.f,0.f};
  if (gate_act) {
    bias = b_ih[gt*HH+u] + b_hh[gt*HH+u];
    #pragma unroll
    for (int r = 0; r < 4; ++r) cst[r] = c0[(size_t)(b0+4*bq+r)*HH + u];
  }
  float pbias0 = 0.f, pbias1 = 0.f;
  if (wid == 7) {
    if (nn < 3*KK - 16) pbias1 = bp[16 + nn];
    pbias0 = bp[nn];
  }

  // weights -> registers, once
  bf16x8 wreg[NKT];
  if (wid < TPW) {
    const __hip_bfloat16* base = gpk + ((size_t)tt*NKT*64 + lane)*8;
    #pragma unroll
    for (int kt = 0; kt < NKT; ++kt) wreg[kt] = *(const bf16x8*)(base + (size_t)kt*512);
  }
  bf16x8 preg[NPF];
  if (wid == 7) {
    const __hip_bfloat16* base = gppk + (size_t)lane*8;
    #pragma unroll
    for (int i = 0; i < NPF; ++i) preg[i] = *(const bf16x8*)(base + (size_t)i*512);
  }

  // prologue: Abuf = [x_0 | w_prev | 0 | h0 | 0]; k-state; scale
  for (int i = tid; i < MB*AST; i += NTHR) {
    int b = i / AST, k = i % AST;
    float v = 0.f;
    if (k < 3) v = strks[(size_t)(b0+b)*(TT*3) + k];
    else if (k < 63) v = w_prev[(size_t)(b0+b)*AA + (k-3)];
    else if (k >= 64 && k < 464) v = h0[(size_t)(b0+b)*HH + (k-64)];
    Abuf[i] = __float2bfloat16(v);
  }
  for (int i = tid; i < KK*MB; i += NTHR)
    kvb[(i>>4)*MB + (i&15)] = k_prev[(size_t)(b0+(i&15))*KK + (i>>4)];
  if (tid < MB) {
    float s = 0.f;
    for (int l = 0; l < SL; ++l) s += sents_m[(size_t)(b0+tid)*SL + l];
    scaleb[tid] = (float)SL / s;
  }

  for (int t = 0; t < TT; ++t) {
    float* hpub = hws + (size_t)((t&1)*NG + g)*(MB*HH);   // [b][u]

    __syncthreads();   // S0: Abuf (w,x from prev iter / prologue) visible

    // ---- P1: gates (15 MFMA) + activations -> hstage fp32
    if (wid < TPW) {
      const __hip_bfloat16* arow = Abuf + nn*AST + bq*8;
      f32x4 acc = {bias,bias,bias,bias};
      #pragma unroll
      for (int kt = 0; kt < NKT; ++kt) {
        bf16x8 af = *(const bf16x8*)(arow + kt*32);
        acc = __builtin_amdgcn_mfma_f32_16x16x32_bf16(af, wreg[kt], acc, 0, 0, 0);
      }
      float vv[4];
      #pragma unroll
      for (int r = 0; r < 4; ++r) {
        float v = acc[r];
        float sg = 1.f/(1.f + __expf(gt==2 ? -2.f*v : -v));
        vv[r] = (gt==2) ? 2.f*sg - 1.f : sg;
      }
      #pragma unroll
      for (int r = 0; r < 4; ++r) {
        float v = vv[r];
        float x4 = __shfl_xor(v,4), x8 = __shfl_xor(v,8), x12 = __shfl_xor(v,12);
        float iv = (gt==0)?v  :(gt==1)?x4 :(gt==2)?x8 :x12;
        float fv = (gt==0)?x4 :(gt==1)?v  :(gt==2)?x12:x8;
        float gv = (gt==0)?x8 :(gt==1)?x12:(gt==2)?v  :x4;
        float ov = (gt==0)?x12:(gt==1)?x8 :(gt==2)?x4 :v;
        float c = fv*cst[r] + iv*gv;
        cst[r] = c;
        float hv = ov * (2.f/(1.f + __expf(-2.f*c)) - 1.f);
        if (gate_act && gt == 0) {
          int bb = 4*bq + r;
          hstage[bb*UPW + wid*4 + du] = hv;
          if (t == TT-1) {
            out[O_HF + (size_t)(b0+bb)*HH + u] = hv;
            out[O_CF + (size_t)(b0+bb)*HH + u] = c;
          }
        }
      }
    }
    __syncthreads();   // S1: hstage ready

    // ---- publish own 28-unit slice, [b][u] contiguous runs (sc1 write-through)
    if (tid < MB*UPW) {
      int b = tid / UPW, ul = tid % UPW;
      int uu = wg*UPW + ul;
      if (uu < HH)
        __hip_atomic_store(hpub + b*HH + uu, hstage[b*UPW + ul],
                           __ATOMIC_RELAXED, __HIP_MEMORY_SCOPE_AGENT);
    }
    __syncthreads();   // S2: every wave's publish stores drained (vmcnt) before flag

    // ---- flag store (relaxed, no RMW, no wbl2) + parallel poll of 16 slots
    if (wid == 0) {
      if (lane == 0)
        __hip_atomic_store(myslot, t+1, __ATOMIC_RELAXED, __HIP_MEMORY_SCOPE_AGENT);
      int ok = 0;
      for (int it = 0; it < (1<<17); ++it) {
        int v = (lane < NWG)
          ? __hip_atomic_load(cnt + (g*NWG + lane)*16, __ATOMIC_RELAXED, __HIP_MEMORY_SCOPE_AGENT)
          : (t+1);
        unsigned long long m = __ballot(v >= t+1);
        if ((m & 0xFFFFull) == 0xFFFFull) { ok = 1; break; }
        __builtin_amdgcn_s_sleep(1);
      }
      if (lane == 0) s_ok = ok;
    }
    __syncthreads();   // S3
    if (!s_ok) return; // loud failure, not a hang

    // ---- P3: read full h_t (fp32) -> Abuf bf16; wg15 streams hid1 coalesced
    for (int i = tid; i < MB*HH; i += NTHR) {
      int b = i / HH, uu = i % HH;
      float v = __hip_atomic_load(hpub + i, __ATOMIC_RELAXED, __HIP_MEMORY_SCOPE_AGENT);
      Abuf[b*AST + 64 + uu] = __float2bfloat16(v);
      if (OUTW)
        __builtin_nontemporal_store(v,
            out + (size_t)(b0+b)*(TT*HH) + (size_t)t*HH + uu);
    }
    if (t+1 < TT && tid >= 464) {
      int idx = tid - 464;                 // 48 threads
      int b = idx/3, cc = idx%3;
      Abuf[b*AST + cc] = __float2bfloat16(
          strks[(size_t)(b0+b)*(TT*3) + (size_t)(t+1)*3 + cc]);
    }
    __syncthreads();   // S4: Abuf h-region ready

    // ---- wave 7: p = h_t @ Wp^T (26 reg-resident MFMA) -> pbuf
    if (wid == 7) {
      const __hip_bfloat16* prow = Abuf + nn*AST + 64 + bq*8;
      f32x4 pa0 = {pbias0,pbias0,pbias0,pbias0};
      f32x4 pa1 = {pbias1,pbias1,pbias1,pbias1};
      #pragma unroll
      for (int kt = 0; kt < 13; ++kt) {
        bf16x8 af = *(const bf16x8*)(prow + kt*32);
        pa0 = __builtin_amdgcn_mfma_f32_16x16x32_bf16(af, preg[kt],    pa0, 0, 0, 0);
        pa1 = __builtin_amdgcn_mfma_f32_16x16x32_bf16(af, preg[13+kt], pa1, 0, 0, 0);
      }
      #pragma unroll
      for (int r = 0; r < 4; ++r) {
        pbuf[nn*MB + 4*bq + r] = pa0[r];
        if (nn < 14) pbuf[(16+nn)*MB + 4*bq + r] = pa1[r];
      }
    }
    __syncthreads();   // S5: pbuf ready

    // ---- window, wave-partitioned: wave w owns batches 2w, 2w+1
    {
      const int bw  = 2*wid + (lane >> 5);
      const int half = lane & 31;
      if (half < 30) {
        float e = __expf(pbuf[half*MB + bw]);
        if (half < 10)      avb[half*MB + bw] = e;
        else if (half < 20) bvb[(half-10)*MB + bw] = e;
        else                kvb[(half-20)*MB + bw] += e;
      }
      for (int uu = half; uu <= SL; uu += 32) {
        float s = 0.f;
        #pragma unroll
        for (int j = 0; j < KK; ++j) {
          float d = kvb[j*MB+bw] - (float)uu;
          s += avb[j*MB+bw] * __expf(-bvb[j*MB+bw]*d*d);
        }
        s *= scaleb[bw];
        phib[bw*66 + uu] = s;
        if (t == TT-1 && OUTW) out[O_PHI + (size_t)(b0+bw)*(SL+1) + uu] = s;
      }
      for (int a = half; a < AA; a += 32) {
        const float* oh = onehots + (size_t)(b0+bw)*(SL*AA) + a;
        float s = 0.f;
        #pragma unroll 8
        for (int l = 0; l < SL; ++l) s += phib[bw*66 + l] * oh[(size_t)l*AA];
        Abuf[bw*AST + 3 + a] = __float2bfloat16(s);
        if (OUTW) {
          __builtin_nontemporal_store(s,
              out + O_WIN + (size_t)(b0+bw)*(TT*AA) + (size_t)t*AA + a);
          if (t == TT-1) out[O_WF + (size_t)(b0+bw)*AA + a] = s;
        }
      }
    }
  }

  __syncthreads();
  if (OUTW && tid < KK*MB)
    out[O_KF + (size_t)(b0+(tid&15))*KK + (tid>>4)] = kvb[(tid>>4)*MB + (tid&15)];
}

extern "C" void kernel_launch(void* const* d_in, const int* in_sizes, int n_in,
                              void* d_out, int out_size, void* d_ws, size_t ws_size,
                              hipStream_t stream) {
  const float* strks   = (const float*)d_in[0];
  const float* onehots = (const float*)d_in[1];
  const float* sents_m = (const float*)d_in[2];
  const float* w_prev  = (const float*)d_in[3];
  const float* k_prev  = (const float*)d_in[4];
  const float* h0      = (const float*)d_in[5];
  const float* c0      = (const float*)d_in[6];
  const float* W_ih    = (const float*)d_in[7];
  const float* b_ih    = (const float*)d_in[8];
  const float* W_hh    = (const float*)d_in[9];
  const float* b_hh    = (const float*)d_in[10];
  const float* Wp      = (const float*)d_in[11];
  const float* bp      = (const float*)d_in[12];

  hipLaunchKernelGGL(zero_cnt, dim3((CNT_N+255)/256), dim3(256), 0, stream, (int*)d_ws);
  int prep_threads = GATE_FRAGS*64 + NPF*64;
  hipLaunchKernelGGL(prep_pack, dim3((prep_threads+255)/256), dim3(256), 0, stream,
                     W_ih, W_hh, Wp, (short*)d_ws);
  hipLaunchKernelGGL(lstm_split, dim3(NG*NWG), dim3(NTHR), 0, stream,
                     strks, onehots, sents_m, w_prev, k_prev, h0, c0,
                     b_ih, b_hh, bp, (float*)d_out, (float*)d_ws);
}

// Round 7
// 14050.597 us; speedup vs baseline: 3.5017x; 1.1205x over previous
//
#include <hip/hip_runtime.h>
#include <hip/hip_bf16.h>
#include <math.h>

#define BATCH 128
#define TT 800
#define SL 64
#define AA 60
#define HH 400
#define KK 10
#define MB 16
#define NG 8
#define NWG 16          // WGs per group
#define NTHR 512
#define TPW 7           // gate tiles per WG (waves 0..6)
#define NTILE (NWG*TPW) // 112 tiles (>=100 dummy)
#define NKT 15          // K tiles: K=480 = [x:3|w:60|0:1|h:400|0:16]
#define AST 488         // Abuf row stride (bf16)
#define NPF 26          // Wp fragments
#define UPW 28          // unit slots per WG (real if <400)

#define O_HF   (BATCH*TT*HH)
#define O_CF   (O_HF + BATCH*HH)
#define O_WIN  (O_CF + BATCH*HH)
#define O_WF   (O_WIN + BATCH*TT*AA)
#define O_KF   (O_WF + BATCH*AA)
#define O_PHI  (O_KF + BATCH*KK)

// ws: cnt slots [NG*NWG][16] ints | hws [2][NG][MB][HH] fp32 | gate pack | Wp pack
#define CNT_N (NG*NWG*16)
#define HWS_F CNT_N
#define HWS_N (2*NG*MB*HH)
#define PK_S  ((CNT_N + HWS_N)*2)
#define GATE_FRAGS (NTILE*NKT)
#define PPK_S (PK_S + GATE_FRAGS*512)

typedef __attribute__((ext_vector_type(8))) short bf16x8;
typedef __attribute__((ext_vector_type(4))) short s16x4;
typedef __attribute__((ext_vector_type(4))) float f32x4;

// 16B agent-coherent load/store (sc1 = agent scope, matches compiler's
// agent-atomic codegen) — relaxed, batched by caller, vmcnt-fenced
__device__ __forceinline__ void llc_ld4(f32x4& r, const float* p) {
  asm volatile("global_load_dwordx4 %0, %1, off sc1" : "=&v"(r) : "v"(p) : "memory");
}
__device__ __forceinline__ void llc_st4(float* p, f32x4 v) {
  asm volatile("global_store_dwordx4 %0, %1, off sc1" :: "v"(p), "v"(v) : "memory");
}
__device__ __forceinline__ void vm_drain() {
  asm volatile("s_waitcnt vmcnt(0)" ::: "memory");
  __builtin_amdgcn_sched_barrier(0);
}

__global__ void zero_cnt(int* c) {
  int i = blockIdx.x*256 + threadIdx.x;
  if (i < CNT_N) c[i] = 0;
}

__global__ void prep_pack(const float* __restrict__ W_ih, const float* __restrict__ W_hh,
                          const float* __restrict__ Wp, short* __restrict__ dst) {
  int tid = blockIdx.x*256 + threadIdx.x;
  const int NWT = GATE_FRAGS*64;
  if (tid < NWT) {
    int l = tid & 63;
    int kt = (tid >> 6) % NKT;
    int tt = (tid >> 6) / NKT;
    int nn = l & 15;
    int gt = nn >> 2, du = nn & 3;
    int u = tt*4 + du;
    int kb = kt*32 + (l>>4)*8;
    __align__(16) short v[8];
    #pragma unroll
    for (int j = 0; j < 8; ++j) {
      int k = kb + j;
      float x = 0.f;
      if (u < HH) {
        if (k < 63) x = W_ih[(size_t)(gt*HH+u)*63 + k];
        else if (k >= 64 && k < 464) x = W_hh[(size_t)(gt*HH+u)*HH + (k-64)];
      }
      __hip_bfloat16 hb = __float2bfloat16(x);
      v[j] = *reinterpret_cast<short*>(&hb);
    }
    *(bf16x8*)(dst + (size_t)PK_S + (size_t)tid*8) = *(const bf16x8*)v;
  } else if (tid < NWT + NPF*64) {
    int r = tid - NWT;
    int l = r & 63;
    int idx = r >> 6;
    int kt = idx % 13;
    int tp = idx / 13;
    int jj = tp*16 + (l&15);
    int kb = (kt+2)*32 + (l>>4)*8;
    __align__(16) short v[8];
    #pragma unroll
    for (int j = 0; j < 8; ++j) {
      int k = kb + j;
      float x = (jj < 3*KK && k >= 64 && k < 464) ? Wp[(size_t)jj*HH + (k-64)] : 0.f;
      __hip_bfloat16 hb = __float2bfloat16(x);
      v[j] = *reinterpret_cast<short*>(&hb);
    }
    *(bf16x8*)(dst + (size_t)PPK_S + (size_t)r*8) = *(const bf16x8*)v;
  }
}

__global__ __launch_bounds__(NTHR, 1) void lstm_split(
    const float* __restrict__ strks, const float* __restrict__ onehots,
    const float* __restrict__ sents_m, const float* __restrict__ w_prev,
    const float* __restrict__ k_prev, const float* __restrict__ h0,
    const float* __restrict__ c0, const float* __restrict__ b_ih,
    const float* __restrict__ b_hh, const float* __restrict__ bp,
    float* __restrict__ out, float* __restrict__ ws)
{
  const int g  = blockIdx.x >> 4;
  const int wg = blockIdx.x & 15;
  const int b0 = g*MB;
  const int tid = threadIdx.x;
  const int lane = tid & 63;
  const int wid = tid >> 6;
  const int nn = lane & 15, gt = nn >> 2, du = nn & 3, bq = lane >> 4;

  int* cnt = (int*)ws;
  int* myslot = cnt + (g*NWG + wg)*16;
  float* hws = ws + HWS_F;
  const __hip_bfloat16* gpk  = (const __hip_bfloat16*)((const short*)ws + PK_S);
  const __hip_bfloat16* gppk = (const __hip_bfloat16*)((const short*)ws + PPK_S);

  __shared__ __align__(16) __hip_bfloat16 Abuf[MB*AST];  // [b][k]
  __shared__ __align__(16) float hstage[MB*UPW];         // [b][u_loc] fp32
  __shared__ float pbuf[30*MB];
  __shared__ float phib[MB*66];
  __shared__ float avb[KK*MB], bvb[KK*MB], kvb[KK*MB];
  __shared__ float scaleb[MB];
  __shared__ int s_ok;

  const int tt = wg*TPW + wid;
  const int u  = (wid < TPW) ? (tt*4 + du) : HH;
  const bool gate_act = (wid < TPW) && (u < HH);
  const bool OUTW = (wg == NWG-1);

  float bias = 0.f, cst[4] = {0.f,0.f,0.f,0.f};
  if (gate_act) {
    bias = b_ih[gt*HH+u] + b_hh[gt*HH+u];
    #pragma unroll
    for (int r = 0; r < 4; ++r) cst[r] = c0[(size_t)(b0+4*bq+r)*HH + u];
  }
  float pbias0 = 0.f, pbias1 = 0.f;
  if (wid == 7) {
    if (nn < 3*KK - 16) pbias1 = bp[16 + nn];
    pbias0 = bp[nn];
  }

  // weights -> registers, once
  bf16x8 wreg[NKT];
  if (wid < TPW) {
    const __hip_bfloat16* base = gpk + ((size_t)tt*NKT*64 + lane)*8;
    #pragma unroll
    for (int kt = 0; kt < NKT; ++kt) wreg[kt] = *(const bf16x8*)(base + (size_t)kt*512);
  }
  bf16x8 preg[NPF];
  if (wid == 7) {
    const __hip_bfloat16* base = gppk + (size_t)lane*8;
    #pragma unroll
    for (int i = 0; i < NPF; ++i) preg[i] = *(const bf16x8*)(base + (size_t)i*512);
  }

  // prologue
  for (int i = tid; i < MB*AST; i += NTHR) {
    int b = i / AST, k = i % AST;
    float v = 0.f;
    if (k < 3) v = strks[(size_t)(b0+b)*(TT*3) + k];
    else if (k < 63) v = w_prev[(size_t)(b0+b)*AA + (k-3)];
    else if (k >= 64 && k < 464) v = h0[(size_t)(b0+b)*HH + (k-64)];
    Abuf[i] = __float2bfloat16(v);
  }
  for (int i = tid; i < KK*MB; i += NTHR)
    kvb[(i>>4)*MB + (i&15)] = k_prev[(size_t)(b0+(i&15))*KK + (i>>4)];
  if (tid < MB) {
    float s = 0.f;
    for (int l = 0; l < SL; ++l) s += sents_m[(size_t)(b0+tid)*SL + l];
    scaleb[tid] = (float)SL / s;
  }

  for (int t = 0; t < TT; ++t) {
    float* hpub = hws + (size_t)((t&1)*NG + g)*(MB*HH);   // [b][u] fp32

    __syncthreads();   // S0: Abuf ready

    // ---- P1: gates (15 MFMA) + activations -> hstage fp32
    if (wid < TPW) {
      const __hip_bfloat16* arow = Abuf + nn*AST + bq*8;
      f32x4 acc = {bias,bias,bias,bias};
      #pragma unroll
      for (int kt = 0; kt < NKT; ++kt) {
        bf16x8 af = *(const bf16x8*)(arow + kt*32);
        acc = __builtin_amdgcn_mfma_f32_16x16x32_bf16(af, wreg[kt], acc, 0, 0, 0);
      }
      float vv[4];
      #pragma unroll
      for (int r = 0; r < 4; ++r) {
        float v = acc[r];
        float sg = 1.f/(1.f + __expf(gt==2 ? -2.f*v : -v));
        vv[r] = (gt==2) ? 2.f*sg - 1.f : sg;
      }
      #pragma unroll
      for (int r = 0; r < 4; ++r) {
        float v = vv[r];
        float x4 = __shfl_xor(v,4), x8 = __shfl_xor(v,8), x12 = __shfl_xor(v,12);
        float iv = (gt==0)?v  :(gt==1)?x4 :(gt==2)?x8 :x12;
        float fv = (gt==0)?x4 :(gt==1)?v  :(gt==2)?x12:x8;
        float gv = (gt==0)?x8 :(gt==1)?x12:(gt==2)?v  :x4;
        float ov = (gt==0)?x12:(gt==1)?x8 :(gt==2)?x4 :v;
        float c = fv*cst[r] + iv*gv;
        cst[r] = c;
        float hv = ov * (2.f/(1.f + __expf(-2.f*c)) - 1.f);
        if (gate_act && gt == 0) {
          int bb = 4*bq + r;
          hstage[bb*UPW + wid*4 + du] = hv;
          if (t == TT-1) {
            out[O_HF + (size_t)(b0+bb)*HH + u] = hv;
            out[O_CF + (size_t)(b0+bb)*HH + u] = c;
          }
        }
      }
    }
    __syncthreads();   // S1: hstage ready

    // ---- publish: one 16B sc1 store per REAL 4-unit chunk (guard vs dummy
    // tiles: wg=14 has only 2 real chunks; unguarded chunks would clobber the
    // next batch's units — that was round 6's correctness bug)
    if (tid < MB*(UPW/4)) {
      int b = tid / (UPW/4), q = tid % (UPW/4);
      int uu0 = wg*UPW + q*4;
      if (uu0 + 3 < HH) {
        f32x4 hv = *(const f32x4*)(hstage + b*UPW + q*4);
        llc_st4(hpub + b*HH + uu0, hv);
      }
    }
    vm_drain();
    __syncthreads();   // S2: all publishes committed before flag

    // ---- flag store + parallel poll (relaxed only, no cache maintenance)
    if (wid == 0) {
      if (lane == 0)
        __hip_atomic_store(myslot, t+1, __ATOMIC_RELAXED, __HIP_MEMORY_SCOPE_AGENT);
      int ok = 0;
      for (int it = 0; it < (1<<17); ++it) {
        int v = (lane < NWG)
          ? __hip_atomic_load(cnt + (g*NWG + lane)*16, __ATOMIC_RELAXED, __HIP_MEMORY_SCOPE_AGENT)
          : (t+1);
        unsigned long long m = __ballot(v >= t+1);
        if ((m & 0xFFFFull) == 0xFFFFull) { ok = 1; break; }
        __builtin_amdgcn_s_sleep(1);
      }
      if (lane == 0) s_ok = ok;
    }
    __syncthreads();   // S3
    if (!s_ok) return;

    // ---- P3: batched 16B sc1 reads of h_t (all in flight), -> Abuf bf16
    {
      f32x4 r0, r1, r2, r3;
      const bool e3 = (tid < 64);             // chunks 1536..1599
      llc_ld4(r0, hpub + 4*tid);
      llc_ld4(r1, hpub + 4*(tid+512));
      llc_ld4(r2, hpub + 4*(tid+1024));
      if (e3) llc_ld4(r3, hpub + 4*(tid+1536));
      vm_drain();

#define CHUNK_STORE(C, R) do {                                                 \
    int gidx = (C)*4, b = gidx/HH, uu = gidx%HH;                               \
    __hip_bfloat16 h0b = __float2bfloat16((R)[0]);                             \
    __hip_bfloat16 h1b = __float2bfloat16((R)[1]);                             \
    __hip_bfloat16 h2b = __float2bfloat16((R)[2]);                             \
    __hip_bfloat16 h3b = __float2bfloat16((R)[3]);                             \
    s16x4 sv = { *(short*)&h0b, *(short*)&h1b, *(short*)&h2b, *(short*)&h3b }; \
    *(s16x4*)(Abuf + b*AST + 64 + uu) = sv;                                    \
    if (OUTW)                                                                  \
      __builtin_nontemporal_store((R),                                         \
          (f32x4*)(out + (size_t)(b0+b)*(TT*HH) + (size_t)t*HH + uu));         \
  } while (0)

      CHUNK_STORE(tid, r0);
      CHUNK_STORE(tid+512, r1);
      CHUNK_STORE(tid+1024, r2);
      if (e3) CHUNK_STORE(tid+1536, r3);
#undef CHUNK_STORE
    }
    if (t+1 < TT && tid >= 464) {
      int idx = tid - 464;
      int b = idx/3, cc = idx%3;
      Abuf[b*AST + cc] = __float2bfloat16(
          strks[(size_t)(b0+b)*(TT*3) + (size_t)(t+1)*3 + cc]);
    }
    __syncthreads();   // S4: Abuf h-region ready

    // ---- wave 7: p = h_t @ Wp^T (reg-resident MFMA) -> pbuf
    if (wid == 7) {
      const __hip_bfloat16* prow = Abuf + nn*AST + 64 + bq*8;
      f32x4 pa0 = {pbias0,pbias0,pbias0,pbias0};
      f32x4 pa1 = {pbias1,pbias1,pbias1,pbias1};
      #pragma unroll
      for (int kt = 0; kt < 13; ++kt) {
        bf16x8 af = *(const bf16x8*)(prow + kt*32);
        pa0 = __builtin_amdgcn_mfma_f32_16x16x32_bf16(af, preg[kt],    pa0, 0, 0, 0);
        pa1 = __builtin_amdgcn_mfma_f32_16x16x32_bf16(af, preg[13+kt], pa1, 0, 0, 0);
      }
      #pragma unroll
      for (int r = 0; r < 4; ++r) {
        pbuf[nn*MB + 4*bq + r] = pa0[r];
        if (nn < 14) pbuf[(16+nn)*MB + 4*bq + r] = pa1[r];
      }
    }
    __syncthreads();   // S5: pbuf ready

    // ---- window, wave-partitioned: wave w owns batches 2w, 2w+1
    {
      const int bw  = 2*wid + (lane >> 5);
      const int half = lane & 31;
      if (half < 30) {
        float e = __expf(pbuf[half*MB + bw]);
        if (half < 10)      avb[half*MB + bw] = e;
        else if (half < 20) bvb[(half-10)*MB + bw] = e;
        else                kvb[(half-20)*MB + bw] += e;
      }
      for (int uu = half; uu <= SL; uu += 32) {
        float s = 0.f;
        #pragma unroll
        for (int j = 0; j < KK; ++j) {
          float d = kvb[j*MB+bw] - (float)uu;
          s += avb[j*MB+bw] * __expf(-bvb[j*MB+bw]*d*d);
        }
        s *= scaleb[bw];
        phib[bw*66 + uu] = s;
        if (t == TT-1 && OUTW) out[O_PHI + (size_t)(b0+bw)*(SL+1) + uu] = s;
      }
      for (int a = half; a < AA; a += 32) {
        const float* oh = onehots + (size_t)(b0+bw)*(SL*AA) + a;
        float s = 0.f;
        #pragma unroll 8
        for (int l = 0; l < SL; ++l) s += phib[bw*66 + l] * oh[(size_t)l*AA];
        Abuf[bw*AST + 3 + a] = __float2bfloat16(s);
        if (OUTW) {
          __builtin_nontemporal_store(s,
              out + O_WIN + (size_t)(b0+bw)*(TT*AA) + (size_t)t*AA + a);
          if (t == TT-1) out[O_WF + (size_t)(b0+bw)*AA + a] = s;
        }
      }
    }
  }

  __syncthreads();
  if (OUTW && tid < KK*MB)
    out[O_KF + (size_t)(b0+(tid&15))*KK + (tid>>4)] = kvb[(tid>>4)*MB + (tid&15)];
}

extern "C" void kernel_launch(void* const* d_in, const int* in_sizes, int n_in,
                              void* d_out, int out_size, void* d_ws, size_t ws_size,
                              hipStream_t stream) {
  const float* strks   = (const float*)d_in[0];
  const float* onehots = (const float*)d_in[1];
  const float* sents_m = (const float*)d_in[2];
  const float* w_prev  = (const float*)d_in[3];
  const float* k_prev  = (const float*)d_in[4];
  const float* h0      = (const float*)d_in[5];
  const float* c0      = (const float*)d_in[6];
  const float* W_ih    = (const float*)d_in[7];
  const float* b_ih    = (const float*)d_in[8];
  const float* W_hh    = (const float*)d_in[9];
  const float* b_hh    = (const float*)d_in[10];
  const float* Wp      = (const float*)d_in[11];
  const float* bp      = (const float*)d_in[12];

  hipLaunchKernelGGL(zero_cnt, dim3((CNT_N+255)/256), dim3(256), 0, stream, (int*)d_ws);
  int prep_threads = GATE_FRAGS*64 + NPF*64;
  hipLaunchKernelGGL(prep_pack, dim3((prep_threads+255)/256), dim3(256), 0, stream,
                     W_ih, W_hh, Wp, (short*)d_ws);
  hipLaunchKernelGGL(lstm_split, dim3(NG*NWG), dim3(NTHR), 0, stream,
                     strks, onehots, sents_m, w_prev, k_prev, h0, c0,
                     b_ih, b_hh, bp, (float*)d_out, (float*)d_ws);
}

// Round 8
// 8125.344 us; speedup vs baseline: 6.0552x; 1.7292x over previous
//
#include <hip/hip_runtime.h>
#include <hip/hip_bf16.h>
#include <math.h>

#define BATCH 128
#define TT 800
#define SL 64
#define AA 60
#define HH 400
#define KK 10
#define MB 16
#define NG 8
#define NWG 16          // WGs per group
#define NTHR 512
#define TPW 7           // gate tiles per WG (waves 0..6)
#define NTILE (NWG*TPW) // 112 tiles (>=100 dummy)
#define NKT 15          // K tiles: K=480 = [x:3|w:60|0:1|h:400|0:16]
#define AST 488         // Abuf row stride (shorts)
#define NPF 26          // Wp fragments

#define O_HF   (BATCH*TT*HH)
#define O_CF   (O_HF + BATCH*HH)
#define O_WIN  (O_CF + BATCH*HH)
#define O_WF   (O_WIN + BATCH*TT*AA)
#define O_KF   (O_WF + BATCH*AA)
#define O_PHI  (O_KF + BATCH*KK)

// ws: tagged h-chunks [2][NG][HH*4 chunks][4 floats] | gate pack | Wp pack
#define CHUNKS_PER_G 6400                 // HH*4 chunks * 4 floats
#define HCH_N (2*NG*CHUNKS_PER_G)         // 102400 floats (zeroed each launch)
#define PK_S  (HCH_N*2)                   // short offset 204800
#define GATE_FRAGS (NTILE*NKT)            // 1680
#define PPK_S (PK_S + GATE_FRAGS*512)

// dynamic LDS partition (bytes, 16B aligned)
#define SM_ABUF  0
#define SM_OHB   (SM_ABUF + MB*AST*2)         // 15616
#define SM_PHIB  (SM_OHB + MB*SL*AA*2)        // 138496
#define SM_PBUF  (SM_PHIB + MB*66*4)          // 142720
#define SM_AVB   (SM_PBUF + 30*MB*4)          // 144640
#define SM_BVB   (SM_AVB + KK*MB*4)           // 145280
#define SM_KVB   (SM_BVB + KK*MB*4)           // 145920
#define SM_SCALE (SM_KVB + KK*MB*4)           // 146560
#define SMEM_BYTES (SM_SCALE + 64)            // 146624

typedef __attribute__((ext_vector_type(8))) short bf16x8;
typedef __attribute__((ext_vector_type(4))) float f32x4;

// 16B agent-coherent load/store (sc1), batched by caller
__device__ __forceinline__ void llc_ld4(f32x4& r, const float* p) {
  asm volatile("global_load_dwordx4 %0, %1, off sc1" : "=&v"(r) : "v"(p) : "memory");
}
__device__ __forceinline__ void llc_st4(float* p, f32x4 v) {
  asm volatile("global_store_dwordx4 %0, %1, off sc1" :: "v"(p), "v"(v) : "memory");
}
__device__ __forceinline__ void vm_drain() {
  asm volatile("s_waitcnt vmcnt(0)" ::: "memory");
  __builtin_amdgcn_sched_barrier(0);
}
__device__ __forceinline__ unsigned bf16bits(float x) {
  __hip_bfloat16 hb = __float2bfloat16(x);
  return (unsigned)*reinterpret_cast<unsigned short*>(&hb);
}

__global__ void prep_pack(const float* __restrict__ W_ih, const float* __restrict__ W_hh,
                          const float* __restrict__ Wp, short* __restrict__ dst) {
  int tid = blockIdx.x*256 + threadIdx.x;
  const int NWT = GATE_FRAGS*64;
  if (tid < NWT) {
    int l = tid & 63;
    int kt = (tid >> 6) % NKT;
    int tt = (tid >> 6) / NKT;
    int nn = l & 15;
    int gt = nn >> 2, du = nn & 3;
    int u = tt*4 + du;
    int kb = kt*32 + (l>>4)*8;
    __align__(16) short v[8];
    #pragma unroll
    for (int j = 0; j < 8; ++j) {
      int k = kb + j;
      float x = 0.f;
      if (u < HH) {
        if (k < 63) x = W_ih[(size_t)(gt*HH+u)*63 + k];
        else if (k >= 64 && k < 464) x = W_hh[(size_t)(gt*HH+u)*HH + (k-64)];
      }
      __hip_bfloat16 hb = __float2bfloat16(x);
      v[j] = *reinterpret_cast<short*>(&hb);
    }
    *(bf16x8*)(dst + (size_t)PK_S + (size_t)tid*8) = *(const bf16x8*)v;
  } else if (tid < NWT + NPF*64) {
    int r = tid - NWT;
    int l = r & 63;
    int idx = r >> 6;
    int kt = idx % 13;
    int tp = idx / 13;
    int jj = tp*16 + (l&15);
    int kb = (kt+2)*32 + (l>>4)*8;
    __align__(16) short v[8];
    #pragma unroll
    for (int j = 0; j < 8; ++j) {
      int k = kb + j;
      float x = (jj < 3*KK && k >= 64 && k < 464) ? Wp[(size_t)jj*HH + (k-64)] : 0.f;
      __hip_bfloat16 hb = __float2bfloat16(x);
      v[j] = *reinterpret_cast<short*>(&hb);
    }
    *(bf16x8*)(dst + (size_t)PPK_S + (size_t)r*8) = *(const bf16x8*)v;
  }
}

__global__ __launch_bounds__(NTHR, 1) void lstm_split(
    const float* __restrict__ strks, const float* __restrict__ onehots,
    const float* __restrict__ sents_m, const float* __restrict__ w_prev,
    const float* __restrict__ k_prev, const float* __restrict__ h0,
    const float* __restrict__ c0, const float* __restrict__ b_ih,
    const float* __restrict__ b_hh, const float* __restrict__ bp,
    float* __restrict__ out, float* __restrict__ ws)
{
  const int g  = blockIdx.x >> 4;
  const int wg = blockIdx.x & 15;
  const int b0 = g*MB;
  const int tid = threadIdx.x;
  const int lane = tid & 63;
  const int wid = tid >> 6;
  const int nn = lane & 15, gt = nn >> 2, du = nn & 3, bq = lane >> 4;

  float* hch = ws;
  const __hip_bfloat16* gpk  = (const __hip_bfloat16*)((const short*)ws + PK_S);
  const __hip_bfloat16* gppk = (const __hip_bfloat16*)((const short*)ws + PPK_S);

  extern __shared__ __align__(16) char smem[];
  __hip_bfloat16* Abuf = (__hip_bfloat16*)(smem + SM_ABUF);   // [b][k]
  __hip_bfloat16* ohb  = (__hip_bfloat16*)(smem + SM_OHB);    // [b][l][a]
  float* phib   = (float*)(smem + SM_PHIB);                   // [b][66]
  float* pbuf   = (float*)(smem + SM_PBUF);                   // [j][b]
  float* avb    = (float*)(smem + SM_AVB);
  float* bvb    = (float*)(smem + SM_BVB);
  float* kvb    = (float*)(smem + SM_KVB);
  float* scaleb = (float*)(smem + SM_SCALE);

  const int tt = wg*TPW + wid;
  const int u  = (wid < TPW) ? (tt*4 + du) : HH;
  const bool gate_act = (wid < TPW) && (u < HH);
  const bool OUTW = (wg == NWG-1);

  float bias = 0.f, cst[4] = {0.f,0.f,0.f,0.f};
  if (gate_act) {
    bias = b_ih[gt*HH+u] + b_hh[gt*HH+u];
    #pragma unroll
    for (int r = 0; r < 4; ++r) cst[r] = c0[(size_t)(b0+4*bq+r)*HH + u];
  }
  float pbias0 = 0.f, pbias1 = 0.f;
  if (wid == 7) {
    if (nn < 3*KK - 16) pbias1 = bp[16 + nn];
    pbias0 = bp[nn];
  }

  // weights -> registers, once
  bf16x8 wreg[NKT];
  if (wid < TPW) {
    const __hip_bfloat16* base = gpk + ((size_t)tt*NKT*64 + lane)*8;
    #pragma unroll
    for (int kt = 0; kt < NKT; ++kt) wreg[kt] = *(const bf16x8*)(base + (size_t)kt*512);
  }
  bf16x8 preg[NPF];
  if (wid == 7) {
    const __hip_bfloat16* base = gppk + (size_t)lane*8;
    #pragma unroll
    for (int i = 0; i < NPF; ++i) preg[i] = *(const bf16x8*)(base + (size_t)i*512);
  }

  // prologue: Abuf = [x_0 | w_prev | 0 | h0 | 0]; onehots->LDS bf16; k; scale
  for (int i = tid; i < MB*AST; i += NTHR) {
    int b = i / AST, k = i % AST;
    float v = 0.f;
    if (k < 3) v = strks[(size_t)(b0+b)*(TT*3) + k];
    else if (k < 63) v = w_prev[(size_t)(b0+b)*AA + (k-3)];
    else if (k >= 64 && k < 464) v = h0[(size_t)(b0+b)*HH + (k-64)];
    Abuf[i] = __float2bfloat16(v);
  }
  for (int i = tid; i < MB*SL*AA; i += NTHR)
    ohb[i] = __float2bfloat16(onehots[(size_t)b0*SL*AA + i]);
  for (int i = tid; i < KK*MB; i += NTHR)
    kvb[(i>>4)*MB + (i&15)] = k_prev[(size_t)(b0+(i&15))*KK + (i>>4)];
  if (tid < MB) {
    float s = 0.f;
    for (int l = 0; l < SL; ++l) s += sents_m[(size_t)(b0+tid)*SL + l];
    scaleb[tid] = (float)SL / s;
  }

  for (int t = 0; t < TT; ++t) {
    float* chb = hch + (size_t)((t&1)*NG + g)*CHUNKS_PER_G;

    __syncthreads();   // S0: Abuf (w,x) ready for P1

    // ---- P1: gates (15 MFMA) + activations; publish tagged chunk directly
    if (wid < TPW) {
      const __hip_bfloat16* arow = Abuf + nn*AST + bq*8;
      f32x4 acc = {bias,bias,bias,bias};
      #pragma unroll
      for (int kt = 0; kt < NKT; ++kt) {
        bf16x8 af = *(const bf16x8*)(arow + kt*32);
        acc = __builtin_amdgcn_mfma_f32_16x16x32_bf16(af, wreg[kt], acc, 0, 0, 0);
      }
      float vv[4], hq[4];
      #pragma unroll
      for (int r = 0; r < 4; ++r) {
        float v = acc[r];
        float sg = 1.f/(1.f + __expf(gt==2 ? -2.f*v : -v));
        vv[r] = (gt==2) ? 2.f*sg - 1.f : sg;
      }
      #pragma unroll
      for (int r = 0; r < 4; ++r) {
        float v = vv[r];
        float x4 = __shfl_xor(v,4), x8 = __shfl_xor(v,8), x12 = __shfl_xor(v,12);
        float iv = (gt==0)?v  :(gt==1)?x4 :(gt==2)?x8 :x12;
        float fv = (gt==0)?x4 :(gt==1)?v  :(gt==2)?x12:x8;
        float gv = (gt==0)?x8 :(gt==1)?x12:(gt==2)?v  :x4;
        float ov = (gt==0)?x12:(gt==1)?x8 :(gt==2)?x4 :v;
        float c = fv*cst[r] + iv*gv;
        cst[r] = c;
        hq[r] = ov * (2.f/(1.f + __expf(-2.f*c)) - 1.f);
      }
      if (gate_act && gt == 0) {
        unsigned q01 = bf16bits(hq[0]) | (bf16bits(hq[1]) << 16);
        unsigned q23 = bf16bits(hq[2]) | (bf16bits(hq[3]) << 16);
        f32x4 ch = { __uint_as_float(q01), __uint_as_float(q23),
                     __int_as_float(t+1), 0.f };
        llc_st4(chb + (size_t)4*(u*4 + bq), ch);   // seq travels WITH data
        if (t == TT-1) {
          #pragma unroll
          for (int r = 0; r < 4; ++r) {
            out[O_HF + (size_t)(b0+4*bq+r)*HH + u] = hq[r];
            out[O_CF + (size_t)(b0+4*bq+r)*HH + u] = cst[r];
          }
        }
      }
    }
    __builtin_amdgcn_s_barrier();   // S1 raw: P1's Abuf reads retired (WAR guard)

    // ---- collect: speculative tagged reads, retry only stale chunks
    {
      const int want = t+1;
      f32x4 c0v, c1v, c2v, c3v;
      int d0=0, d1=0, d2=0, d3=(tid < 64) ? 0 : 1;
      for (int it = 0; it < (1<<12); ++it) {
        if (!d0) llc_ld4(c0v, chb + 4*(size_t)tid);
        if (!d1) llc_ld4(c1v, chb + 4*(size_t)(tid+512));
        if (!d2) llc_ld4(c2v, chb + 4*(size_t)(tid+1024));
        if (!d3) llc_ld4(c3v, chb + 4*(size_t)(tid+1536));
        vm_drain();
        d0 |= (__float_as_int(c0v.z) == want);
        d1 |= (__float_as_int(c1v.z) == want);
        d2 |= (__float_as_int(c2v.z) == want);
        d3 |= (__float_as_int(c3v.z) == want);
        if (d0 & d1 & d2 & d3) break;
      }
#define UNPACK(C, CID) do {                                                    \
    int uu = (CID) >> 2, bb = ((CID) & 3) * 4;                                 \
    unsigned p01 = __float_as_uint((C).x), p23 = __float_as_uint((C).y);       \
    short* ab = (short*)Abuf;                                                  \
    ab[(bb+0)*AST + 64 + uu] = (short)(p01 & 0xffff);                          \
    ab[(bb+1)*AST + 64 + uu] = (short)(p01 >> 16);                             \
    ab[(bb+2)*AST + 64 + uu] = (short)(p23 & 0xffff);                          \
    ab[(bb+3)*AST + 64 + uu] = (short)(p23 >> 16);                             \
    if (OUTW) {                                                                \
      float* op = out + (size_t)(b0+bb)*(TT*HH) + (size_t)t*HH + uu;           \
      __builtin_nontemporal_store(__uint_as_float(p01 << 16), op);             \
      __builtin_nontemporal_store(__uint_as_float(p01 & 0xffff0000u), op + (size_t)TT*HH); \
      __builtin_nontemporal_store(__uint_as_float(p23 << 16), op + 2*(size_t)TT*HH);       \
      __builtin_nontemporal_store(__uint_as_float(p23 & 0xffff0000u), op + 3*(size_t)TT*HH); \
    }                                                                          \
  } while (0)
      UNPACK(c0v, tid);
      UNPACK(c1v, tid+512);
      UNPACK(c2v, tid+1024);
      if (tid < 64) UNPACK(c3v, tid+1536);
#undef UNPACK
    }
    if (t+1 < TT && tid >= 464) {
      int idx = tid - 464;
      int b = idx/3, cc = idx%3;
      Abuf[b*AST + cc] = __float2bfloat16(
          strks[(size_t)(b0+b)*(TT*3) + (size_t)(t+1)*3 + cc]);
    }
    __syncthreads();   // S4: Abuf h-region complete

    // ---- wave 7: p = h_t @ Wp^T (reg-resident MFMA) -> pbuf
    if (wid == 7) {
      const __hip_bfloat16* prow = Abuf + nn*AST + 64 + bq*8;
      f32x4 pa0 = {pbias0,pbias0,pbias0,pbias0};
      f32x4 pa1 = {pbias1,pbias1,pbias1,pbias1};
      #pragma unroll
      for (int kt = 0; kt < 13; ++kt) {
        bf16x8 af = *(const bf16x8*)(prow + kt*32);
        pa0 = __builtin_amdgcn_mfma_f32_16x16x32_bf16(af, preg[kt],    pa0, 0, 0, 0);
        pa1 = __builtin_amdgcn_mfma_f32_16x16x32_bf16(af, preg[13+kt], pa1, 0, 0, 0);
      }
      #pragma unroll
      for (int r = 0; r < 4; ++r) {
        pbuf[nn*MB + 4*bq + r] = pa0[r];
        if (nn < 14) pbuf[(16+nn)*MB + 4*bq + r] = pa1[r];
      }
    }
    __syncthreads();   // S5: pbuf ready

    // ---- window, wave-partitioned: wave w owns batches 2w, 2w+1
    {
      const int bw  = 2*wid + (lane >> 5);
      const int half = lane & 31;
      if (half < 30) {
        float e = __expf(pbuf[half*MB + bw]);
        if (half < 10)      avb[half*MB + bw] = e;
        else if (half < 20) bvb[(half-10)*MB + bw] = e;
        else                kvb[(half-20)*MB + bw] += e;
      }
      for (int uu = half; uu <= SL; uu += 32) {
        float s = 0.f;
        #pragma unroll
        for (int j = 0; j < KK; ++j) {
          float d = kvb[j*MB+bw] - (float)uu;
          s += avb[j*MB+bw] * __expf(-bvb[j*MB+bw]*d*d);
        }
        s *= scaleb[bw];
        phib[bw*66 + uu] = s;
        if (t == TT-1 && OUTW) out[O_PHI + (size_t)(b0+bw)*(SL+1) + uu] = s;
      }
      const __hip_bfloat16* ohrow = ohb + (size_t)bw*SL*AA;
      for (int a = half; a < AA; a += 32) {
        float s = 0.f;
        #pragma unroll 8
        for (int l = 0; l < SL; ++l)
          s += phib[bw*66 + l] * __bfloat162float(ohrow[(size_t)l*AA + a]);
        Abuf[bw*AST + 3 + a] = __float2bfloat16(s);
        if (OUTW) {
          __builtin_nontemporal_store(s,
              out + O_WIN + (size_t)(b0+bw)*(TT*AA) + (size_t)t*AA + a);
          if (t == TT-1) out[O_WF + (size_t)(b0+bw)*AA + a] = s;
        }
      }
    }
  }

  __syncthreads();
  if (OUTW && tid < KK*MB)
    out[O_KF + (size_t)(b0+(tid&15))*KK + (tid>>4)] = kvb[(tid>>4)*MB + (tid&15)];
}

extern "C" void kernel_launch(void* const* d_in, const int* in_sizes, int n_in,
                              void* d_out, int out_size, void* d_ws, size_t ws_size,
                              hipStream_t stream) {
  const float* strks   = (const float*)d_in[0];
  const float* onehots = (const float*)d_in[1];
  const float* sents_m = (const float*)d_in[2];
  const float* w_prev  = (const float*)d_in[3];
  const float* k_prev  = (const float*)d_in[4];
  const float* h0      = (const float*)d_in[5];
  const float* c0      = (const float*)d_in[6];
  const float* W_ih    = (const float*)d_in[7];
  const float* b_ih    = (const float*)d_in[8];
  const float* W_hh    = (const float*)d_in[9];
  const float* b_hh    = (const float*)d_in[10];
  const float* Wp      = (const float*)d_in[11];
  const float* bp      = (const float*)d_in[12];

  // raise dynamic-LDS cap (idempotent; not a stream op, graph-capture safe)
  hipFuncSetAttribute((const void*)lstm_split,
                      hipFuncAttributeMaxDynamicSharedMemorySize, SMEM_BYTES);
  // zero the tagged-chunk region so stale seqs from prior replays can't match
  hipMemsetAsync(d_ws, 0, HCH_N*4, stream);
  int prep_threads = GATE_FRAGS*64 + NPF*64;
  hipLaunchKernelGGL(prep_pack, dim3((prep_threads+255)/256), dim3(256), 0, stream,
                     W_ih, W_hh, Wp, (short*)d_ws);
  hipLaunchKernelGGL(lstm_split, dim3(NG*NWG), dim3(NTHR), SMEM_BYTES, stream,
                     strks, onehots, sents_m, w_prev, k_prev, h0, c0,
                     b_ih, b_hh, bp, (float*)d_out, (float*)d_ws);
}

// Round 9
// 6152.617 us; speedup vs baseline: 7.9967x; 1.3206x over previous
//
#include <hip/hip_runtime.h>
#include <hip/hip_bf16.h>
#include <math.h>

#define BATCH 128
#define TT 800
#define SL 64
#define AA 60
#define HH 400
#define KK 10
#define MB 16
#define NG 8
#define NWG 16          // WGs per group
#define NTHR 512
#define TPW 7           // gate tiles per WG (waves 0..6)
#define NTILE (NWG*TPW) // 112 tiles (>=100 dummy)
#define NKT 15          // K tiles: K=480 = [x:3|w:60|0:1|h:400|0:16]
#define AST 488         // Abuf row stride (shorts)
#define NPF 26          // Wp fragments
#define OHST 72         // transposed onehots l-stride (16B-aligned rows)

#define O_HF   (BATCH*TT*HH)
#define O_CF   (O_HF + BATCH*HH)
#define O_WIN  (O_CF + BATCH*HH)
#define O_WF   (O_WIN + BATCH*TT*AA)
#define O_KF   (O_WF + BATCH*AA)
#define O_PHI  (O_KF + BATCH*KK)

// ws: tagged h-chunks [2][NG][1600 chunks][4 floats] | gate pack | Wp pack
#define CHUNKS_PER_G 6400
#define HCH_N (2*NG*CHUNKS_PER_G)
#define PK_S  (HCH_N*2)
#define GATE_FRAGS (NTILE*NKT)
#define PPK_S (PK_S + GATE_FRAGS*512)

// dynamic LDS partition (bytes)
#define SM_ABUF  0
#define SM_OHB   (SM_ABUF + MB*AST*2)          // 15616
#define SM_PHIB  (SM_OHB + MB*AA*OHST*2)       // 153856
#define SM_PBUF  (SM_PHIB + MB*66*4)           // 158080
#define SM_AVB   (SM_PBUF + 30*MB*4)           // 160000
#define SM_BVB   (SM_AVB + KK*MB*4)            // 160640
#define SM_KVB   (SM_BVB + KK*MB*4)            // 161280
#define SM_SCALE (SM_KVB + KK*MB*4)            // 161920
#define SMEM_BYTES (SM_SCALE + 64)             // 161984 <= 163840

typedef __attribute__((ext_vector_type(8))) short bf16x8;
typedef __attribute__((ext_vector_type(4))) float f32x4;
typedef __attribute__((ext_vector_type(4))) unsigned u32x4;

__device__ __forceinline__ void llc_ld4(f32x4& r, const float* p) {
  asm volatile("global_load_dwordx4 %0, %1, off sc1" : "=&v"(r) : "v"(p) : "memory");
}
__device__ __forceinline__ void llc_st4(float* p, f32x4 v) {
  asm volatile("global_store_dwordx4 %0, %1, off sc1" :: "v"(p), "v"(v) : "memory");
}
__device__ __forceinline__ void vm_drain() {
  asm volatile("s_waitcnt vmcnt(0)" ::: "memory");
  __builtin_amdgcn_sched_barrier(0);
}
__device__ __forceinline__ unsigned bf16bits(float x) {
  __hip_bfloat16 hb = __float2bfloat16(x);
  return (unsigned)*reinterpret_cast<unsigned short*>(&hb);
}

__global__ void prep_pack(const float* __restrict__ W_ih, const float* __restrict__ W_hh,
                          const float* __restrict__ Wp, short* __restrict__ dst) {
  int tid = blockIdx.x*256 + threadIdx.x;
  const int NWT = GATE_FRAGS*64;
  if (tid < NWT) {
    int l = tid & 63;
    int kt = (tid >> 6) % NKT;
    int tt = (tid >> 6) / NKT;
    int nn = l & 15;
    int gt = nn >> 2, du = nn & 3;
    int u = tt*4 + du;
    int kb = kt*32 + (l>>4)*8;
    __align__(16) short v[8];
    #pragma unroll
    for (int j = 0; j < 8; ++j) {
      int k = kb + j;
      float x = 0.f;
      if (u < HH) {
        if (k < 63) x = W_ih[(size_t)(gt*HH+u)*63 + k];
        else if (k >= 64 && k < 464) x = W_hh[(size_t)(gt*HH+u)*HH + (k-64)];
      }
      __hip_bfloat16 hb = __float2bfloat16(x);
      v[j] = *reinterpret_cast<short*>(&hb);
    }
    *(bf16x8*)(dst + (size_t)PK_S + (size_t)tid*8) = *(const bf16x8*)v;
  } else if (tid < NWT + NPF*64) {
    int r = tid - NWT;
    int l = r & 63;
    int idx = r >> 6;
    int kt = idx % 13;
    int tp = idx / 13;
    int jj = tp*16 + (l&15);
    int kb = (kt+2)*32 + (l>>4)*8;
    __align__(16) short v[8];
    #pragma unroll
    for (int j = 0; j < 8; ++j) {
      int k = kb + j;
      float x = (jj < 3*KK && k >= 64 && k < 464) ? Wp[(size_t)jj*HH + (k-64)] : 0.f;
      __hip_bfloat16 hb = __float2bfloat16(x);
      v[j] = *reinterpret_cast<short*>(&hb);
    }
    *(bf16x8*)(dst + (size_t)PPK_S + (size_t)r*8) = *(const bf16x8*)v;
  }
}

__global__ __launch_bounds__(NTHR, 1) void lstm_split(
    const float* __restrict__ strks, const float* __restrict__ onehots,
    const float* __restrict__ sents_m, const float* __restrict__ w_prev,
    const float* __restrict__ k_prev, const float* __restrict__ h0,
    const float* __restrict__ c0, const float* __restrict__ b_ih,
    const float* __restrict__ b_hh, const float* __restrict__ bp,
    float* __restrict__ out, float* __restrict__ ws)
{
  const int g  = blockIdx.x >> 4;
  const int wg = blockIdx.x & 15;
  const int b0 = g*MB;
  const int tid = threadIdx.x;
  const int lane = tid & 63;
  const int wid = tid >> 6;
  const int nn = lane & 15, gt = nn >> 2, du = nn & 3, bq = lane >> 4;

  float* hch = ws;
  const __hip_bfloat16* gpk  = (const __hip_bfloat16*)((const short*)ws + PK_S);
  const __hip_bfloat16* gppk = (const __hip_bfloat16*)((const short*)ws + PPK_S);

  extern __shared__ __align__(16) char smem[];
  __hip_bfloat16* Abuf = (__hip_bfloat16*)(smem + SM_ABUF);   // [b][k]
  __hip_bfloat16* ohb  = (__hip_bfloat16*)(smem + SM_OHB);    // [b][a][OHST]
  float* phib   = (float*)(smem + SM_PHIB);                   // [b][66]
  float* pbuf   = (float*)(smem + SM_PBUF);                   // [j][b]
  float* avb    = (float*)(smem + SM_AVB);
  float* bvb    = (float*)(smem + SM_BVB);
  float* kvb    = (float*)(smem + SM_KVB);
  float* scaleb = (float*)(smem + SM_SCALE);

  const int tt = wg*TPW + wid;
  const int u  = (wid < TPW) ? (tt*4 + du) : HH;
  const bool gate_act = (wid < TPW) && (u < HH);
  const bool OUTW = (wg == NWG-1);

  float bias = 0.f, cst[4] = {0.f,0.f,0.f,0.f};
  if (gate_act) {
    bias = b_ih[gt*HH+u] + b_hh[gt*HH+u];
    #pragma unroll
    for (int r = 0; r < 4; ++r) cst[r] = c0[(size_t)(b0+4*bq+r)*HH + u];
  }
  float pbias0 = 0.f, pbias1 = 0.f;
  if (wid == 7) {
    if (nn < 3*KK - 16) pbias1 = bp[16 + nn];
    pbias0 = bp[nn];
  }

  // weights -> registers, once
  bf16x8 wreg[NKT];
  if (wid < TPW) {
    const __hip_bfloat16* base = gpk + ((size_t)tt*NKT*64 + lane)*8;
    #pragma unroll
    for (int kt = 0; kt < NKT; ++kt) wreg[kt] = *(const bf16x8*)(base + (size_t)kt*512);
  }
  bf16x8 preg[NPF];
  if (wid == 7) {
    const __hip_bfloat16* base = gppk + (size_t)lane*8;
    #pragma unroll
    for (int i = 0; i < NPF; ++i) preg[i] = *(const bf16x8*)(base + (size_t)i*512);
  }

  // prologue: Abuf = [x_0 | w_prev | 0 | h0 | 0]; ohb transposed; k; scale
  for (int i = tid; i < MB*AST; i += NTHR) {
    int b = i / AST, k = i % AST;
    float v = 0.f;
    if (k < 3) v = strks[(size_t)(b0+b)*(TT*3) + k];
    else if (k < 63) v = w_prev[(size_t)(b0+b)*AA + (k-3)];
    else if (k >= 64 && k < 464) v = h0[(size_t)(b0+b)*HH + (k-64)];
    Abuf[i] = __float2bfloat16(v);
  }
  for (int i = tid; i < MB*SL*AA; i += NTHR) {
    int b = i / (SL*AA), r = i % (SL*AA);
    int l = r / AA, a = r % AA;
    ohb[(b*AA + a)*OHST + l] = __float2bfloat16(onehots[(size_t)b0*SL*AA + i]);
  }
  for (int i = tid; i < KK*MB; i += NTHR)
    kvb[(i>>4)*MB + (i&15)] = k_prev[(size_t)(b0+(i&15))*KK + (i>>4)];
  if (tid < MB) {
    float s = 0.f;
    for (int l = 0; l < SL; ++l) s += sents_m[(size_t)(b0+tid)*SL + l];
    scaleb[tid] = (float)SL / s;
  }
  __syncthreads();

#define ACT_PUBLISH(ACC, CHB, SEQTAG, WRITE_FINAL) do {                        \
    float vv[4], hq[4];                                                        \
    _Pragma("unroll") for (int r = 0; r < 4; ++r) {                            \
      float v = (ACC)[r];                                                      \
      float sg = 1.f/(1.f + __expf(gt==2 ? -2.f*v : -v));                      \
      vv[r] = (gt==2) ? 2.f*sg - 1.f : sg;                                     \
    }                                                                          \
    _Pragma("unroll") for (int r = 0; r < 4; ++r) {                            \
      float v = vv[r];                                                         \
      float x4 = __shfl_xor(v,4), x8 = __shfl_xor(v,8), x12 = __shfl_xor(v,12);\
      float iv = (gt==0)?v  :(gt==1)?x4 :(gt==2)?x8 :x12;                      \
      float fv = (gt==0)?x4 :(gt==1)?v  :(gt==2)?x12:x8;                       \
      float gv = (gt==0)?x8 :(gt==1)?x12:(gt==2)?v  :x4;                       \
      float ov = (gt==0)?x12:(gt==1)?x8 :(gt==2)?x4 :v;                        \
      float c = fv*cst[r] + iv*gv;                                             \
      cst[r] = c;                                                              \
      hq[r] = ov * (2.f/(1.f + __expf(-2.f*c)) - 1.f);                         \
    }                                                                          \
    if (gate_act && gt == 0) {                                                 \
      unsigned q01 = bf16bits(hq[0]) | (bf16bits(hq[1]) << 16);                \
      unsigned q23 = bf16bits(hq[2]) | (bf16bits(hq[3]) << 16);                \
      f32x4 ch = { __uint_as_float(q01), __uint_as_float(q23),                 \
                   __int_as_float(SEQTAG), 0.f };                              \
      llc_st4((CHB) + (size_t)4*(u*4 + bq), ch);                               \
      if (WRITE_FINAL) {                                                       \
        _Pragma("unroll") for (int r = 0; r < 4; ++r) {                        \
          out[O_HF + (size_t)(b0+4*bq+r)*HH + u] = hq[r];                      \
          out[O_CF + (size_t)(b0+4*bq+r)*HH + u] = cst[r];                     \
        }                                                                      \
      }                                                                        \
    }                                                                          \
  } while (0)

  // prologue gates: full K (h0 is in Abuf) -> publish h_0 (tag 1, parity 0)
  f32x4 gacc;
  if (wid < TPW) {
    const __hip_bfloat16* arow = Abuf + nn*AST + bq*8;
    gacc = (f32x4){bias,bias,bias,bias};
    #pragma unroll
    for (int kt = 0; kt < NKT; ++kt) {
      bf16x8 af = *(const bf16x8*)(arow + kt*32);
      gacc = __builtin_amdgcn_mfma_f32_16x16x32_bf16(af, wreg[kt], gacc, 0, 0, 0);
    }
    ACT_PUBLISH(gacc, hch + (size_t)g*CHUNKS_PER_G, 1, false);
  }
  __syncthreads();   // prologue h-region reads done before collect overwrites

  for (int s = 0; s < TT; ++s) {
    float* chb = hch + (size_t)(((s  )&1)*NG + g)*CHUNKS_PER_G;  // h_s
    float* chn = hch + (size_t)(((s+1)&1)*NG + g)*CHUNKS_PER_G;  // h_{s+1}

    // ---- collect h_s: speculative tagged reads, retry only stale chunks
    {
      const int want = s+1;
      f32x4 c0v, c1v, c2v, c3v;
      int d0=0, d1=0, d2=0, d3=(tid < 64) ? 0 : 1;
      for (int it = 0; it < (1<<12); ++it) {
        if (!d0) llc_ld4(c0v, chb + 4*(size_t)tid);
        if (!d1) llc_ld4(c1v, chb + 4*(size_t)(tid+512));
        if (!d2) llc_ld4(c2v, chb + 4*(size_t)(tid+1024));
        if (!d3) llc_ld4(c3v, chb + 4*(size_t)(tid+1536));
        vm_drain();
        d0 |= (__float_as_int(c0v.z) == want);
        d1 |= (__float_as_int(c1v.z) == want);
        d2 |= (__float_as_int(c2v.z) == want);
        d3 |= (__float_as_int(c3v.z) == want);
        if (d0 & d1 & d2 & d3) break;
      }
#define UNPACK(C, CID) do {                                                    \
    int uu = (CID) >> 2, bb = ((CID) & 3) * 4;                                 \
    unsigned p01 = __float_as_uint((C).x), p23 = __float_as_uint((C).y);       \
    short* ab = (short*)Abuf;                                                  \
    ab[(bb+0)*AST + 64 + uu] = (short)(p01 & 0xffff);                          \
    ab[(bb+1)*AST + 64 + uu] = (short)(p01 >> 16);                             \
    ab[(bb+2)*AST + 64 + uu] = (short)(p23 & 0xffff);                          \
    ab[(bb+3)*AST + 64 + uu] = (short)(p23 >> 16);                             \
    if (OUTW) {                                                                \
      float* op = out + (size_t)(b0+bb)*(TT*HH) + (size_t)s*HH + uu;           \
      __builtin_nontemporal_store(__uint_as_float(p01 << 16), op);             \
      __builtin_nontemporal_store(__uint_as_float(p01 & 0xffff0000u), op + (size_t)TT*HH); \
      __builtin_nontemporal_store(__uint_as_float(p23 << 16), op + 2*(size_t)TT*HH);       \
      __builtin_nontemporal_store(__uint_as_float(p23 & 0xffff0000u), op + 3*(size_t)TT*HH); \
    }                                                                          \
  } while (0)
      UNPACK(c0v, tid);
      UNPACK(c1v, tid+512);
      UNPACK(c2v, tid+1024);
      if (tid < 64) UNPACK(c3v, tid+1536);
#undef UNPACK
    }
    float xr = 0.f;                      // x_{s+1} -> reg (latency hides here)
    if (s+1 < TT && tid < MB*3)
      xr = strks[(size_t)(b0 + tid/3)*(TT*3) + (size_t)(s+1)*3 + (tid%3)];
    __syncthreads();   // S4: Abuf h-region complete

    // ---- wave 7: p_s = Wp·h_s  ||  waves 0-6: h-part of gates_{s+1}
    if (wid == 7) {
      const __hip_bfloat16* prow = Abuf + nn*AST + 64 + bq*8;
      f32x4 pa0 = {pbias0,pbias0,pbias0,pbias0};
      f32x4 pa1 = {pbias1,pbias1,pbias1,pbias1};
      #pragma unroll
      for (int kt = 0; kt < 13; ++kt) {
        bf16x8 af = *(const bf16x8*)(prow + kt*32);
        pa0 = __builtin_amdgcn_mfma_f32_16x16x32_bf16(af, preg[kt],    pa0, 0, 0, 0);
        pa1 = __builtin_amdgcn_mfma_f32_16x16x32_bf16(af, preg[13+kt], pa1, 0, 0, 0);
      }
      #pragma unroll
      for (int r = 0; r < 4; ++r) {
        pbuf[nn*MB + 4*bq + r] = pa0[r];
        if (nn < 14) pbuf[(16+nn)*MB + 4*bq + r] = pa1[r];
      }
    } else if (s+1 < TT) {
      const __hip_bfloat16* arow = Abuf + nn*AST + bq*8;
      gacc = (f32x4){bias,bias,bias,bias};
      #pragma unroll
      for (int kt = 2; kt < NKT; ++kt) {
        bf16x8 af = *(const bf16x8*)(arow + kt*32);
        gacc = __builtin_amdgcn_mfma_f32_16x16x32_bf16(af, wreg[kt], gacc, 0, 0, 0);
      }
    }
    __syncthreads();   // S5: pbuf ready

    // ---- window (all 8 waves; wave w owns batches 2w, 2w+1)
    if (s+1 < TT && tid < MB*3)
      Abuf[(tid/3)*AST + (tid%3)] = __float2bfloat16(xr);   // stage x_{s+1}
    {
      const int bw  = 2*wid + (lane >> 5);
      const int half = lane & 31;
      if (half < 30) {
        float e = __expf(pbuf[half*MB + bw]);
        if (half < 10)      avb[half*MB + bw] = e;
        else if (half < 20) bvb[(half-10)*MB + bw] = e;
        else                kvb[(half-20)*MB + bw] += e;
      }
      for (int uu = half; uu <= SL; uu += 32) {
        float sv = 0.f;
        #pragma unroll
        for (int j = 0; j < KK; ++j) {
          float d = kvb[j*MB+bw] - (float)uu;
          sv += avb[j*MB+bw] * __expf(-bvb[j*MB+bw]*d*d);
        }
        sv *= scaleb[bw];
        phib[bw*66 + uu] = sv;
        if (s == TT-1 && OUTW) out[O_PHI + (size_t)(b0+bw)*(SL+1) + uu] = sv;
      }
      for (int a = half; a < AA; a += 32) {
        const u32x4* orow = (const u32x4*)(ohb + (bw*AA + a)*OHST);
        const float* ph = phib + bw*66;
        float sv = 0.f;
        #pragma unroll
        for (int c = 0; c < 8; ++c) {
          u32x4 v = orow[c];
          #pragma unroll
          for (int q = 0; q < 4; ++q) {
            unsigned p = v[q];
            sv = fmaf(__uint_as_float(p << 16),        ph[c*8 + 2*q],     sv);
            sv = fmaf(__uint_as_float(p & 0xffff0000u), ph[c*8 + 2*q + 1], sv);
          }
        }
        Abuf[bw*AST + 3 + a] = __float2bfloat16(sv);
        if (OUTW) {
          __builtin_nontemporal_store(sv,
              out + O_WIN + (size_t)(b0+bw)*(TT*AA) + (size_t)s*AA + a);
          if (s == TT-1) out[O_WF + (size_t)(b0+bw)*AA + a] = sv;
        }
      }
    }
    __syncthreads();   // S6: w_s (+x_{s+1}) staged in Abuf

    // ---- xw-part of gates_{s+1} + activations + publish h_{s+1}
    if (s+1 < TT && wid < TPW) {
      const __hip_bfloat16* arow = Abuf + nn*AST + bq*8;
      #pragma unroll
      for (int kt = 0; kt < 2; ++kt) {
        bf16x8 af = *(const bf16x8*)(arow + kt*32);
        gacc = __builtin_amdgcn_mfma_f32_16x16x32_bf16(af, wreg[kt], gacc, 0, 0, 0);
      }
      ACT_PUBLISH(gacc, chn, s+2, (s+1 == TT-1));
    }
    // no barrier: collect(s+1) writes only h-region/regs; xw reads k<64 only
  }
#undef ACT_PUBLISH

  __syncthreads();
  if (OUTW && tid < KK*MB)
    out[O_KF + (size_t)(b0+(tid&15))*KK + (tid>>4)] = kvb[(tid>>4)*MB + (tid&15)];
}

extern "C" void kernel_launch(void* const* d_in, const int* in_sizes, int n_in,
                              void* d_out, int out_size, void* d_ws, size_t ws_size,
                              hipStream_t stream) {
  const float* strks   = (const float*)d_in[0];
  const float* onehots = (const float*)d_in[1];
  const float* sents_m = (const float*)d_in[2];
  const float* w_prev  = (const float*)d_in[3];
  const float* k_prev  = (const float*)d_in[4];
  const float* h0      = (const float*)d_in[5];
  const float* c0      = (const float*)d_in[6];
  const float* W_ih    = (const float*)d_in[7];
  const float* b_ih    = (const float*)d_in[8];
  const float* W_hh    = (const float*)d_in[9];
  const float* b_hh    = (const float*)d_in[10];
  const float* Wp      = (const float*)d_in[11];
  const float* bp      = (const float*)d_in[12];

  hipFuncSetAttribute((const void*)lstm_split,
                      hipFuncAttributeMaxDynamicSharedMemorySize, SMEM_BYTES);
  hipMemsetAsync(d_ws, 0, HCH_N*4, stream);   // stale-seq guard across replays
  int prep_threads = GATE_FRAGS*64 + NPF*64;
  hipLaunchKernelGGL(prep_pack, dim3((prep_threads+255)/256), dim3(256), 0, stream,
                     W_ih, W_hh, Wp, (short*)d_ws);
  hipLaunchKernelGGL(lstm_split, dim3(NG*NWG), dim3(NTHR), SMEM_BYTES, stream,
                     strks, onehots, sents_m, w_prev, k_prev, h0, c0,
                     b_ih, b_hh, bp, (float*)d_out, (float*)d_ws);
}